// Round 11
// baseline (250.018 us; speedup 1.0000x reference)
//
#include <hip/hip_runtime.h>
#include <hip/hip_bf16.h>
#include <cstdint>
#include <cstddef>

// ---------------------------------------------------------------------------
// MGCN (2-layer relational GCN + linear head), FUSED gather+GEMM version.
//
// Per layer, one kernel: each block owns 32 dst nodes.
//   Phase 1: gather-aggregate s_in/s_out for those nodes into two swizzled
//            32x256 bf16 LDS tiles (no global intermediate!).
//   Phase 2: K=768 GEMM.  K-steps 0-3 (x part) stream x via a double-buffered
//            LDS tile (R8 pipeline, B prefetched one step ahead); K-steps
//            4-11 read A-fragments straight from the LDS agg tiles.
//   Epilogue: h = x + res*tanh(acc+b), coalesced via LDS staging.
//   HEAD=true adds the mu_w GEMM on the h2 tile (never touches HBM).
// ---------------------------------------------------------------------------

typedef short bf16x8 __attribute__((ext_vector_type(8)));
typedef float f32x4  __attribute__((ext_vector_type(4)));

__device__ __forceinline__ float b2f(unsigned short u) {
    union { unsigned u32; float f; } c; c.u32 = ((unsigned)u) << 16; return c.f;
}
__device__ __forceinline__ unsigned short f2b(float f) {
    union { float f; unsigned u; } c; c.f = f;
    unsigned r = c.u + 0x7FFFu + ((c.u >> 16) & 1u);   // RNE
    return (unsigned short)(r >> 16);
}
__device__ __forceinline__ float ftanh(float x) {
    float e = __expf(2.0f * x);
    return 1.0f - __fdividef(2.0f, e + 1.0f);
}

// ---- CSR construction ------------------------------------------------------

__global__ void k_hist(const int* __restrict__ dst, int* __restrict__ cnt, int E) {
    int i = blockIdx.x * blockDim.x + threadIdx.x;
    if (i < E) atomicAdd(&cnt[dst[i]], 1);
}

__global__ void k_norm(const int* __restrict__ cnt, float* __restrict__ norm, int N) {
    int i = blockIdx.x * blockDim.x + threadIdx.x;
    if (i < N) norm[i] = 1.0f / fmaxf((float)cnt[i], 1.0f);
}

__global__ void k_scan1(const int* __restrict__ cnt, int* __restrict__ part,
                        int* __restrict__ bsum, int N) {
    __shared__ int s[256];
    int i = blockIdx.x * 256 + threadIdx.x;
    int v = (i < N) ? cnt[i] : 0;
    s[threadIdx.x] = v; __syncthreads();
    #pragma unroll
    for (int o = 1; o < 256; o <<= 1) {
        int t = (threadIdx.x >= o) ? s[threadIdx.x - o] : 0;
        __syncthreads();
        s[threadIdx.x] += t;
        __syncthreads();
    }
    if (i < N) part[i] = s[threadIdx.x] - v;
    if (threadIdx.x == 255) bsum[blockIdx.x] = s[255];
}

__global__ void k_scan2(int* __restrict__ bsum, int nb) {
    __shared__ int s[256];
    int v = (threadIdx.x < nb) ? bsum[threadIdx.x] : 0;
    s[threadIdx.x] = v; __syncthreads();
    #pragma unroll
    for (int o = 1; o < 256; o <<= 1) {
        int t = (threadIdx.x >= o) ? s[threadIdx.x - o] : 0;
        __syncthreads();
        s[threadIdx.x] += t;
        __syncthreads();
    }
    if (threadIdx.x < nb) bsum[threadIdx.x] = s[threadIdx.x] - v;
}

__global__ void k_scan3(const int* __restrict__ part, const int* __restrict__ bsum,
                        int* __restrict__ rowptr, int* __restrict__ cursor, int N, int E) {
    int i = blockIdx.x * 256 + threadIdx.x;
    if (i < N) {
        int r = part[i] + bsum[blockIdx.x];
        rowptr[i] = r; cursor[i] = r;
    }
    if (i == 0) rowptr[N] = E;
}

__global__ void k_scatter(const int* __restrict__ src, const int* __restrict__ dst,
                          const int* __restrict__ et, int* __restrict__ cursor,
                          unsigned* __restrict__ erec, int E, int halfE) {
    int e = blockIdx.x * blockDim.x + threadIdx.x;
    if (e < E) {
        int d = dst[e];
        int pos = atomicAdd(&cursor[d], 1);
        unsigned rec = (unsigned)src[e] | ((unsigned)et[e] << 16)
                     | ((e >= halfE) ? 0x80000000u : 0u);
        erec[pos] = rec;
    }
}

// ---- dtype prep ------------------------------------------------------------

__global__ void k_cvt3(const float* __restrict__ s0, unsigned short* __restrict__ d0, long n0,
                       const float* __restrict__ s1, unsigned short* __restrict__ d1, long n1,
                       const float* __restrict__ s2, unsigned short* __restrict__ d2, long n2) {
    long i = (long)blockIdx.x * blockDim.x + threadIdx.x;
    const float* s; unsigned short* d; long j = i;
    if (j < n0) { s = s0; d = d0; }
    else {
        j -= n0;
        if (j < n1) { s = s1; d = d1; }
        else { j -= n1; if (j >= n2) return; s = s2; d = d2; }
    }
    float4 v = ((const float4*)s)[j];
    ushort4 o;
    o.x = f2b(v.x); o.y = f2b(v.y); o.z = f2b(v.z); o.w = f2b(v.w);
    ((ushort4*)d)[j] = o;
}

// Repack 7 W[256][256] (row-major f32) into MFMA-B fragment layout bf16.
__global__ void k_wfrag7(const float* __restrict__ w0, const float* __restrict__ w1,
                         const float* __restrict__ w2, const float* __restrict__ w3,
                         const float* __restrict__ w4, const float* __restrict__ w5,
                         const float* __restrict__ w6, unsigned short* __restrict__ out) {
    int o = blockIdx.x * 256 + threadIdx.x;      // grid = 7*65536/256
    int mi = o >> 16;
    int r  = o & 65535;
    const float* W = (mi == 0) ? w0 : (mi == 1) ? w1 : (mi == 2) ? w2 :
                     (mi == 3) ? w3 : (mi == 4) ? w4 : (mi == 5) ? w5 : w6;
    int j  = r & 7;
    int l  = (r >> 3) & 63;
    int nn = (r >> 9) & 15;
    int kg = r >> 13;
    int k = kg * 32 + (l >> 4) * 8 + j;
    int n = nn * 16 + (l & 15);
    out[o] = f2b(W[k * 256 + n]);
}

// ---- fused gather + GEMM (+ optional head) --------------------------------

#define BPREF(SN, Bn)                                                          \
  do {                                                                         \
    const int pn_ = (SN) >> 2, cbn_ = (SN) & 3;                                \
    const unsigned short* __restrict__ Wn_ = Wf + (size_t)pn_ * 65536;         \
    _Pragma("unroll")                                                          \
    for (int kk_ = 0; kk_ < 2; ++kk_) {                                        \
      _Pragma("unroll")                                                        \
      for (int n_ = 0; n_ < 4; ++n_) {                                         \
        Bn[kk_ * 4 + n_] = *(const bf16x8*)(Wn_ +                              \
            ((((cbn_ * 2 + kk_) * 16 + (w * 4 + n_)) * 64 + l) * 8));          \
      }                                                                        \
    }                                                                          \
  } while (0)

#define XMFMA(AtC, Bc)                                                         \
  do {                                                                         \
    _Pragma("unroll")                                                          \
    for (int kk_ = 0; kk_ < 2; ++kk_) {                                        \
      bf16x8 a_[2];                                                            \
      _Pragma("unroll")                                                        \
      for (int m_ = 0; m_ < 2; ++m_) {                                         \
        int rm_ = 16 * m_ + lr;                                                \
        int ch_ = (kk_ * 4 + lq) ^ (rm_ & 7);                                  \
        a_[m_] = *(const bf16x8*)(&AtC[rm_ * 64 + ch_ * 8]);                   \
      }                                                                        \
      _Pragma("unroll")                                                        \
      for (int m_ = 0; m_ < 2; ++m_) {                                         \
        _Pragma("unroll")                                                      \
        for (int n_ = 0; n_ < 4; ++n_) {                                       \
          acc[m_][n_] = __builtin_amdgcn_mfma_f32_16x16x32_bf16(a_[m_], Bc[kk_ * 4 + n_], acc[m_][n_], 0, 0, 0); \
        }                                                                      \
      }                                                                        \
    }                                                                          \
  } while (0)

#define SMFMA(TILE, CB, Bc)                                                    \
  do {                                                                         \
    _Pragma("unroll")                                                          \
    for (int kk_ = 0; kk_ < 2; ++kk_) {                                        \
      bf16x8 a_[2];                                                            \
      _Pragma("unroll")                                                        \
      for (int m_ = 0; m_ < 2; ++m_) {                                         \
        int rm_ = 16 * m_ + lr;                                                \
        int ch_ = ((CB) * 8 + kk_ * 4 + lq) ^ (rm_ & 7);                       \
        a_[m_] = *(const bf16x8*)(&TILE[rm_ * 256 + ch_ * 8]);                 \
      }                                                                        \
      _Pragma("unroll")                                                        \
      for (int m_ = 0; m_ < 2; ++m_) {                                         \
        _Pragma("unroll")                                                      \
        for (int n_ = 0; n_ < 4; ++n_) {                                       \
          acc[m_][n_] = __builtin_amdgcn_mfma_f32_16x16x32_bf16(a_[m_], Bc[kk_ * 4 + n_], acc[m_][n_], 0, 0, 0); \
        }                                                                      \
      }                                                                        \
    }                                                                          \
  } while (0)

#define FENCE_BAR                                                              \
  asm volatile("s_waitcnt lgkmcnt(0)" ::: "memory");                           \
  __builtin_amdgcn_sched_barrier(0);                                           \
  __builtin_amdgcn_s_barrier();                                                \
  __builtin_amdgcn_sched_barrier(0);

template <bool HEAD>
__global__ __launch_bounds__(256, 2)
void k_fused(const unsigned short* __restrict__ a0,    // [N,256] bf16 (x / h1)
             const unsigned short* __restrict__ relb,  // [R,256] bf16
             const int* __restrict__ rowptr,
             const unsigned* __restrict__ erec,
             const float* __restrict__ norm,
             const unsigned short* __restrict__ Wf,    // frag layout, 3*65536
             const float* __restrict__ bias,
             const float* __restrict__ resPtr,
             const unsigned short* __restrict__ WfMu,  // frag layout (HEAD)
             const float* __restrict__ mub,            // [256] (HEAD)
             float* __restrict__ outF,                 // [N,256] f32 (HEAD)
             unsigned short* __restrict__ outB,        // [N,256] bf16 (!HEAD)
             int N, int D)
{
    __shared__ unsigned short sAgg0[32 * 256];   // 16 KB  s_in tile (swizzled)
    __shared__ unsigned short sAgg1[32 * 256];   // 16 KB  s_out tile (swizzled)
    __shared__ unsigned short xt[2][32 * 64];    //  8 KB  x K-step dbuf

    const int t = threadIdx.x;
    const int rBase = blockIdx.x * 32;
    const int w  = t >> 6;
    const int l  = t & 63;
    const int lr = l & 15;
    const int lq = l >> 4;

    // x staging geometry: one 16B chunk per thread (32 rows x 8 chunks)
    const int rS = t >> 3;
    const int cS = t & 7;
    const int wo = rS * 64 + ((cS ^ (rS & 7)) * 8);
    const size_t g = (size_t)min(rBase + rS, N - 1) * 256 + cS * 8;

    // issue x tiles 0..2 + B(step0) before the gather phase; they stay in flight
    uint4 Ra = *(const uint4*)(a0 + g);
    uint4 Rb = *(const uint4*)(a0 + g + 64);
    uint4 Rc = *(const uint4*)(a0 + g + 128);
    bf16x8 B0[8], B1[8];
    #pragma unroll
    for (int kk = 0; kk < 2; ++kk) {
        #pragma unroll
        for (int n = 0; n < 4; ++n)
            B0[kk * 4 + n] = *(const bf16x8*)(Wf + (((kk * 16 + (w * 4 + n)) * 64 + l) * 8));
    }

    // ---- phase 1: gather-aggregate 8 nodes per wave into sAgg tiles ----
    #pragma unroll 1
    for (int i = 0; i < 8; ++i) {
        const int r = w * 8 + i;
        const int v = rBase + r;
        float ai0 = 0, ai1 = 0, ai2 = 0, ai3 = 0;
        float ao0 = 0, ao1 = 0, ao2 = 0, ao3 = 0;
        float nm = 0.0f;
        if (v < N) {
            const int rs = rowptr[v], re = rowptr[v + 1];
            nm = norm[v];
            unsigned c0 = (rs     < re) ? erec[rs]     : 0u;
            unsigned c1 = (rs + 1 < re) ? erec[rs + 1] : 0u;
            int idx = rs;
            while (idx + 2 <= re) {
                unsigned n0 = (idx + 2 < re) ? erec[idx + 2] : 0u;
                unsigned n1 = (idx + 3 < re) ? erec[idx + 3] : 0u;
                ushort4 x0 = *(const ushort4*)(a0   + (size_t)(c0 & 0xffff) * 256 + l * 4);
                ushort4 r0 = *(const ushort4*)(relb + (size_t)((c0 >> 16) & 0x7fff) * 256 + l * 4);
                ushort4 x1 = *(const ushort4*)(a0   + (size_t)(c1 & 0xffff) * 256 + l * 4);
                ushort4 r1 = *(const ushort4*)(relb + (size_t)((c1 >> 16) & 0x7fff) * 256 + l * 4);
                float p0 = b2f(x0.x) * b2f(r0.x), p1 = b2f(x0.y) * b2f(r0.y);
                float p2 = b2f(x0.z) * b2f(r0.z), p3 = b2f(x0.w) * b2f(r0.w);
                if (c0 >> 31) { ao0 += p0; ao1 += p1; ao2 += p2; ao3 += p3; }
                else          { ai0 += p0; ai1 += p1; ai2 += p2; ai3 += p3; }
                p0 = b2f(x1.x) * b2f(r1.x); p1 = b2f(x1.y) * b2f(r1.y);
                p2 = b2f(x1.z) * b2f(r1.z); p3 = b2f(x1.w) * b2f(r1.w);
                if (c1 >> 31) { ao0 += p0; ao1 += p1; ao2 += p2; ao3 += p3; }
                else          { ai0 += p0; ai1 += p1; ai2 += p2; ai3 += p3; }
                c0 = n0; c1 = n1; idx += 2;
            }
            if (idx < re) {
                ushort4 x0 = *(const ushort4*)(a0   + (size_t)(c0 & 0xffff) * 256 + l * 4);
                ushort4 r0 = *(const ushort4*)(relb + (size_t)((c0 >> 16) & 0x7fff) * 256 + l * 4);
                float p0 = b2f(x0.x) * b2f(r0.x), p1 = b2f(x0.y) * b2f(r0.y);
                float p2 = b2f(x0.z) * b2f(r0.z), p3 = b2f(x0.w) * b2f(r0.w);
                if (c0 >> 31) { ao0 += p0; ao1 += p1; ao2 += p2; ao3 += p3; }
                else          { ai0 += p0; ai1 += p1; ai2 += p2; ai3 += p3; }
            }
        }
        ushort4 oi, oo;
        oi.x = f2b(ai0 * nm); oi.y = f2b(ai1 * nm); oi.z = f2b(ai2 * nm); oi.w = f2b(ai3 * nm);
        oo.x = f2b(ao0 * nm); oo.y = f2b(ao1 * nm); oo.z = f2b(ao2 * nm); oo.w = f2b(ao3 * nm);
        const int base = r * 256 + (((l >> 1) ^ (r & 7)) * 8) + (l & 1) * 4;
        *(ushort4*)(&sAgg0[base]) = oi;
        *(ushort4*)(&sAgg1[base]) = oo;
    }
    __syncthreads();                      // sAgg tiles complete, block-wide

    // ---- phase 2: K = 768 GEMM ----
    f32x4 acc[2][4] = {};

    // x pipeline prologue: tile 0 -> xt[0]
    *(uint4*)(&xt[0][wo]) = Ra;
    FENCE_BAR

    // step 0..3 : x part (barrier-pipelined dbuf)
    *(uint4*)(&xt[1][wo]) = Rb;
    BPREF(1, B1);
    XMFMA(xt[0], B0);
    Ra = *(const uint4*)(a0 + g + 192);
    FENCE_BAR

    *(uint4*)(&xt[0][wo]) = Rc;
    BPREF(2, B0);
    XMFMA(xt[1], B1);
    FENCE_BAR

    *(uint4*)(&xt[1][wo]) = Ra;
    BPREF(3, B1);
    XMFMA(xt[0], B0);
    FENCE_BAR

    BPREF(4, B0);
    XMFMA(xt[1], B1);

    // step 4..11 : s_in / s_out parts straight from LDS (no barriers)
    BPREF(5,  B1); SMFMA(sAgg0, 0, B0);
    BPREF(6,  B0); SMFMA(sAgg0, 1, B1);
    BPREF(7,  B1); SMFMA(sAgg0, 2, B0);
    BPREF(8,  B0); SMFMA(sAgg0, 3, B1);
    BPREF(9,  B1); SMFMA(sAgg1, 0, B0);
    BPREF(10, B0); SMFMA(sAgg1, 1, B1);
    BPREF(11, B1); SMFMA(sAgg1, 2, B0);
                   SMFMA(sAgg1, 3, B1);

    const int rb4 = lq * 4;
    const float resv = resPtr[0];

    if (!HEAD) {
        // ---- coalesced epilogue: stage res*tanh(acc+bias) in LDS halves ----
        unsigned short* C = sAgg0;               // 32 x 128 bf16 per half
        #pragma unroll
        for (int half = 0; half < 2; ++half) {
            __syncthreads();                     // protect sAgg reuse / half swap
            if ((w >> 1) == half) {
                #pragma unroll
                for (int m = 0; m < 2; ++m) {
                    #pragma unroll
                    for (int i = 0; i < 4; ++i) {
                        int r6 = 16 * m + rb4 + i;
                        #pragma unroll
                        for (int n = 0; n < 4; ++n) {
                            int cH = (w & 1) * 64 + lr + 16 * n;
                            float v = acc[m][n][i] + bias[half * 128 + cH];
                            C[r6 * 128 + cH] = f2b(resv * ftanh(v));
                        }
                    }
                }
            }
            __syncthreads();
            #pragma unroll
            for (int ii = 0; ii < 2; ++ii) {
                int g2  = ii * 256 + t;          // 512 chunks total
                int r   = g2 >> 4;               // 16 chunks per row
                int cc  = g2 & 15;
                int row = rBase + r;
                if (row < N) {
                    bf16x8 sv = *(const bf16x8*)(&C[r * 128 + cc * 8]);
                    const unsigned short* ar = a0 + (size_t)row * D + half * 128 + cc * 8;
                    uint4 av = *(const uint4*)ar;
                    unsigned aw[4] = { av.x, av.y, av.z, av.w };
                    unsigned ow[4];
                    #pragma unroll
                    for (int p = 0; p < 4; ++p) {
                        float h0 = b2f((unsigned short)(aw[p] & 0xffff)) + b2f((unsigned short)sv[2 * p]);
                        float h1 = b2f((unsigned short)(aw[p] >> 16))    + b2f((unsigned short)sv[2 * p + 1]);
                        ow[p] = (unsigned)f2b(h0) | ((unsigned)f2b(h1) << 16);
                    }
                    *(uint4*)(outB + (size_t)row * D + half * 128 + cc * 8) =
                        make_uint4(ow[0], ow[1], ow[2], ow[3]);
                }
            }
        }
    } else {
        // ---- HEAD: h2 -> swizzled sAgg0 tile, then out = h2 @ WfMu + mub ----
        __syncthreads();                         // all SMFMA reads of sAgg done
        #pragma unroll
        for (int m = 0; m < 2; ++m) {
            #pragma unroll
            for (int i = 0; i < 4; ++i) {
                int row = rBase + 16 * m + rb4 + i;
                if (row < N) {
                    size_t base = (size_t)row * D + w * 64 + lr;
                    int r6 = 16 * m + rb4 + i;
                    #pragma unroll
                    for (int n = 0; n < 4; ++n) {
                        int   c = w * 64 + lr + 16 * n;
                        float v = acc[m][n][i] + bias[c];
                        float h = b2f(a0[base + 16 * n]) + resv * ftanh(v);
                        sAgg0[r6 * 256 + (c ^ ((r6 & 7) << 3))] = f2b(h);
                    }
                }
            }
        }
        __syncthreads();
        #pragma unroll
        for (int m = 0; m < 2; ++m) {
            #pragma unroll
            for (int n = 0; n < 4; ++n)
                acc[m][n] = (f32x4){0.f, 0.f, 0.f, 0.f};
        }

        #pragma unroll
        for (int s2 = 0; s2 < 4; ++s2) {
            #pragma unroll
            for (int kk = 0; kk < 2; ++kk) {
                const int kg = s2 * 2 + kk;
                bf16x8 a_[2], b_[4];
                #pragma unroll
                for (int m = 0; m < 2; ++m) {
                    int rm = 16 * m + lr;
                    int ch = (s2 * 8 + kk * 4 + lq) ^ (rm & 7);
                    a_[m] = *(const bf16x8*)(&sAgg0[rm * 256 + ch * 8]);
                }
                #pragma unroll
                for (int n = 0; n < 4; ++n)
                    b_[n] = *(const bf16x8*)(WfMu + (((kg * 16 + (w * 4 + n)) * 64 + l) * 8));
                #pragma unroll
                for (int m = 0; m < 2; ++m) {
                    #pragma unroll
                    for (int n = 0; n < 4; ++n)
                        acc[m][n] = __builtin_amdgcn_mfma_f32_16x16x32_bf16(a_[m], b_[n], acc[m][n], 0, 0, 0);
                }
            }
        }

        // coalesced f32 store via sAgg1 staging (32 x 128 f32 per half)
        float* Cf = (float*)sAgg1;
        #pragma unroll
        for (int half = 0; half < 2; ++half) {
            __syncthreads();
            if ((w >> 1) == half) {
                #pragma unroll
                for (int m = 0; m < 2; ++m) {
                    #pragma unroll
                    for (int i = 0; i < 4; ++i) {
                        int r6 = 16 * m + rb4 + i;
                        #pragma unroll
                        for (int n = 0; n < 4; ++n) {
                            int cH = (w & 1) * 64 + lr + 16 * n;
                            Cf[r6 * 128 + cH] = acc[m][n][i] + mub[half * 128 + cH];
                        }
                    }
                }
            }
            __syncthreads();
            #pragma unroll
            for (int ii = 0; ii < 4; ++ii) {
                int g2  = ii * 256 + t;          // 1024 float4-chunks total
                int r   = g2 >> 5;               // 32 chunks per row
                int cc  = g2 & 31;
                int row = rBase + r;
                if (row < N) {
                    *(float4*)(outF + (size_t)row * D + half * 128 + cc * 4) =
                        *(const float4*)(&Cf[r * 128 + cc * 4]);
                }
            }
        }
    }
}

// ---------------------------------------------------------------------------

extern "C" void kernel_launch(void* const* d_in, const int* in_sizes, int n_in,
                              void* d_out, int out_size, void* d_ws, size_t ws_size,
                              hipStream_t stream)
{
    const float* emb  = (const float*)d_in[0];
    const int*   ei   = (const int*)  d_in[1];
    const int*   et   = (const int*)  d_in[2];
    const float* rel1 = (const float*)d_in[3];
    const float* Wi1  = (const float*)d_in[4];
    const float* Wo1  = (const float*)d_in[5];
    const float* Wl1  = (const float*)d_in[6];
    const float* b1   = (const float*)d_in[7];
    const float* rel2 = (const float*)d_in[8];
    const float* Wi2  = (const float*)d_in[9];
    const float* Wo2  = (const float*)d_in[10];
    const float* Wl2  = (const float*)d_in[11];
    const float* b2   = (const float*)d_in[12];
    const float* res  = (const float*)d_in[13];
    const float* muw  = (const float*)d_in[14];
    const float* mub  = (const float*)d_in[15];

    const int D = in_sizes[7];          // 256
    const int N = in_sizes[0] / D;      // 50000
    const int E = in_sizes[2];          // 320000
    const int R = in_sizes[3] / D;      // 400
    const int halfE = E / 2;
    const int* srcA = ei;
    const int* dstA = ei + E;
    const size_t DD = (size_t)D * D;

    char* ws = (char*)d_ws;
    size_t off = 0;
    auto alloc = [&](size_t bytes) -> char* {
        char* p = ws + off; off += (bytes + 255) & ~(size_t)255; return p;
    };
    const int nb1 = (N + 255) / 256;

    float*          norm   = (float*)          alloc((size_t)N * 4);
    int*            cnt    = (int*)            alloc((size_t)N * 4);
    int*            rowptr = (int*)            alloc((size_t)(N + 1) * 4);
    int*            cursor = (int*)            alloc((size_t)N * 4);
    int*            part   = (int*)            alloc((size_t)N * 4);
    int*            bsum   = (int*)            alloc(1024);
    unsigned*       erec   = (unsigned*)       alloc((size_t)E * 4);
    unsigned short* xb     = (unsigned short*) alloc((size_t)N * D * 2);
    unsigned short* h1b    = (unsigned short*) alloc((size_t)N * D * 2);
    unsigned short* r1b    = (unsigned short*) alloc((size_t)R * D * 2);
    unsigned short* r2b    = (unsigned short*) alloc((size_t)R * D * 2);
    unsigned short* fAll   = (unsigned short*) alloc(7 * DD * 2);
    if (off > ws_size) return;

    unsigned short* fW1 = fAll;            // [Wl1, Wi1, Wo1]
    unsigned short* fW2 = fAll + 3 * DD;   // [Wl2, Wi2, Wo2]
    unsigned short* fMu = fAll + 6 * DD;

    // --- CSR + norm ---
    hipMemsetAsync(cnt, 0, (size_t)N * 4, stream);
    k_hist   <<<(E + 255) / 256, 256, 0, stream>>>(dstA, cnt, E);
    k_norm   <<<nb1, 256, 0, stream>>>(cnt, norm, N);
    k_scan1  <<<nb1, 256, 0, stream>>>(cnt, part, bsum, N);
    k_scan2  <<<1,   256, 0, stream>>>(bsum, nb1);
    k_scan3  <<<nb1, 256, 0, stream>>>(part, bsum, rowptr, cursor, N, E);
    k_scatter<<<(E + 255) / 256, 256, 0, stream>>>(srcA, dstA, et, cursor, erec, E, halfE);

    // --- dtype prep ---
    long nd4 = (long)N * D / 4, rd4 = (long)R * D / 4;
    long tot4 = nd4 + 2 * rd4;
    k_cvt3<<<(int)((tot4 + 255) / 256), 256, 0, stream>>>(
        emb, xb, nd4, rel1, r1b, rd4, rel2, r2b, rd4);
    k_wfrag7<<<(int)(7 * DD / 256), 256, 0, stream>>>(
        Wl1, Wi1, Wo1, Wl2, Wi2, Wo2, muw, fAll);

    const int NB = (N + 31) / 32;   // 32-row fused blocks

    // --- layer 1 (fused gather + GEMM) ---
    k_fused<false><<<NB, 256, 0, stream>>>(xb, r1b, rowptr, erec, norm, fW1, b1, res,
                                           nullptr, nullptr, nullptr, h1b, N, D);

    // --- layer 2 + head (fused gather + GEMM + mu) ---
    k_fused<true><<<NB, 256, 0, stream>>>(h1b, r2b, rowptr, erec, norm, fW2, b2, res,
                                          fMu, mub, (float*)d_out, nullptr, N, D);
}

// Round 12
// 245.657 us; speedup vs baseline: 1.0178x; 1.0178x over previous
//
#include <hip/hip_runtime.h>
#include <hip/hip_bf16.h>
#include <cstdint>
#include <cstddef>

// ---------------------------------------------------------------------------
// MGCN (2-layer relational GCN + linear head), split agg/GEMM (R8 structure).
//
//   Layer 1 (EXPERIMENT): k_agg2 (half-wave edge-split gather) +
//                         k_gemm512 (8-wave blocks, single-B pipeline).
//   Layer 2 + head (CONTROL): R8 k_agg + k_gemm<true> (B double-buffered).
// ---------------------------------------------------------------------------

typedef short bf16x8 __attribute__((ext_vector_type(8)));
typedef float f32x4  __attribute__((ext_vector_type(4)));

__device__ __forceinline__ float b2f(unsigned short u) {
    union { unsigned u32; float f; } c; c.u32 = ((unsigned)u) << 16; return c.f;
}
__device__ __forceinline__ unsigned short f2b(float f) {
    union { float f; unsigned u; } c; c.f = f;
    unsigned r = c.u + 0x7FFFu + ((c.u >> 16) & 1u);   // RNE
    return (unsigned short)(r >> 16);
}
__device__ __forceinline__ float ftanh(float x) {
    float e = __expf(2.0f * x);
    return 1.0f - __fdividef(2.0f, e + 1.0f);
}

// ---- CSR construction ------------------------------------------------------

__global__ void k_hist(const int* __restrict__ dst, int* __restrict__ cnt, int E) {
    int i = blockIdx.x * blockDim.x + threadIdx.x;
    if (i < E) atomicAdd(&cnt[dst[i]], 1);
}

__global__ void k_norm(const int* __restrict__ cnt, float* __restrict__ norm, int N) {
    int i = blockIdx.x * blockDim.x + threadIdx.x;
    if (i < N) norm[i] = 1.0f / fmaxf((float)cnt[i], 1.0f);
}

__global__ void k_scan1(const int* __restrict__ cnt, int* __restrict__ part,
                        int* __restrict__ bsum, int N) {
    __shared__ int s[256];
    int i = blockIdx.x * 256 + threadIdx.x;
    int v = (i < N) ? cnt[i] : 0;
    s[threadIdx.x] = v; __syncthreads();
    #pragma unroll
    for (int o = 1; o < 256; o <<= 1) {
        int t = (threadIdx.x >= o) ? s[threadIdx.x - o] : 0;
        __syncthreads();
        s[threadIdx.x] += t;
        __syncthreads();
    }
    if (i < N) part[i] = s[threadIdx.x] - v;
    if (threadIdx.x == 255) bsum[blockIdx.x] = s[255];
}

__global__ void k_scan2(int* __restrict__ bsum, int nb) {
    __shared__ int s[256];
    int v = (threadIdx.x < nb) ? bsum[threadIdx.x] : 0;
    s[threadIdx.x] = v; __syncthreads();
    #pragma unroll
    for (int o = 1; o < 256; o <<= 1) {
        int t = (threadIdx.x >= o) ? s[threadIdx.x - o] : 0;
        __syncthreads();
        s[threadIdx.x] += t;
        __syncthreads();
    }
    if (threadIdx.x < nb) bsum[threadIdx.x] = s[threadIdx.x] - v;
}

__global__ void k_scan3(const int* __restrict__ part, const int* __restrict__ bsum,
                        int* __restrict__ rowptr, int* __restrict__ cursor, int N, int E) {
    int i = blockIdx.x * 256 + threadIdx.x;
    if (i < N) {
        int r = part[i] + bsum[blockIdx.x];
        rowptr[i] = r; cursor[i] = r;
    }
    if (i == 0) rowptr[N] = E;
}

__global__ void k_scatter(const int* __restrict__ src, const int* __restrict__ dst,
                          const int* __restrict__ et, int* __restrict__ cursor,
                          unsigned* __restrict__ erec, int E, int halfE) {
    int e = blockIdx.x * blockDim.x + threadIdx.x;
    if (e < E) {
        int d = dst[e];
        int pos = atomicAdd(&cursor[d], 1);
        unsigned rec = (unsigned)src[e] | ((unsigned)et[e] << 16)
                     | ((e >= halfE) ? 0x80000000u : 0u);
        erec[pos] = rec;
    }
}

// ---- dtype prep ------------------------------------------------------------

__global__ void k_cvt3(const float* __restrict__ s0, unsigned short* __restrict__ d0, long n0,
                       const float* __restrict__ s1, unsigned short* __restrict__ d1, long n1,
                       const float* __restrict__ s2, unsigned short* __restrict__ d2, long n2) {
    long i = (long)blockIdx.x * blockDim.x + threadIdx.x;
    const float* s; unsigned short* d; long j = i;
    if (j < n0) { s = s0; d = d0; }
    else {
        j -= n0;
        if (j < n1) { s = s1; d = d1; }
        else { j -= n1; if (j >= n2) return; s = s2; d = d2; }
    }
    float4 v = ((const float4*)s)[j];
    ushort4 o;
    o.x = f2b(v.x); o.y = f2b(v.y); o.z = f2b(v.z); o.w = f2b(v.w);
    ((ushort4*)d)[j] = o;
}

// Repack 7 W[256][256] (row-major f32) into MFMA-B fragment layout bf16.
__global__ void k_wfrag7(const float* __restrict__ w0, const float* __restrict__ w1,
                         const float* __restrict__ w2, const float* __restrict__ w3,
                         const float* __restrict__ w4, const float* __restrict__ w5,
                         const float* __restrict__ w6, unsigned short* __restrict__ out) {
    int o = blockIdx.x * 256 + threadIdx.x;      // grid = 7*65536/256
    int mi = o >> 16;
    int r  = o & 65535;
    const float* W = (mi == 0) ? w0 : (mi == 1) ? w1 : (mi == 2) ? w2 :
                     (mi == 3) ? w3 : (mi == 4) ? w4 : (mi == 5) ? w5 : w6;
    int j  = r & 7;
    int l  = (r >> 3) & 63;
    int nn = (r >> 9) & 15;
    int kg = r >> 13;
    int k = kg * 32 + (l >> 4) * 8 + j;
    int n = nn * 16 + (l & 15);
    out[o] = f2b(W[k * 256 + n]);
}

// ---- EXPERIMENT: half-wave edge-split gather -------------------------------
// Lane half h=l>>5 handles edge i+h (16B = 8 cols per lane, 32 lanes/row).
// 4 edges in flight per iteration; __shfl_xor(.,32) combines halves.

__global__ __launch_bounds__(256)
void k_agg2(const unsigned short* __restrict__ xb, const unsigned short* __restrict__ relb,
            const int* __restrict__ rowptr, const unsigned* __restrict__ erec,
            const float* __restrict__ norm,
            unsigned short* __restrict__ sIn, unsigned short* __restrict__ sOut,
            int N, int D)
{
    const int w = threadIdx.x >> 6, l = threadIdx.x & 63;
    const int v = blockIdx.x * 4 + w;
    if (v >= N) return;
    const int rs = rowptr[v], re = rowptr[v + 1];
    const float nm = norm[v];
    const int h  = l >> 5;
    const int sl = l & 31;

    float ai[8] = {}, ao[8] = {};

    #pragma unroll 1
    for (int i = rs; i < re; i += 4) {
        const int e0 = i + h, e1 = i + 2 + h;
        const unsigned c0 = (e0 < re) ? erec[e0] : 0u;
        const unsigned c1 = (e1 < re) ? erec[e1] : 0u;
        uint4 x0 = make_uint4(0,0,0,0), r0 = make_uint4(0,0,0,0);
        uint4 x1 = make_uint4(0,0,0,0), r1 = make_uint4(0,0,0,0);
        if (e0 < re) {
            x0 = *(const uint4*)(xb   + (size_t)(c0 & 0xffff) * 256 + sl * 8);
            r0 = *(const uint4*)(relb + (size_t)((c0 >> 16) & 0x7fff) * 256 + sl * 8);
        }
        if (e1 < re) {
            x1 = *(const uint4*)(xb   + (size_t)(c1 & 0xffff) * 256 + sl * 8);
            r1 = *(const uint4*)(relb + (size_t)((c1 >> 16) & 0x7fff) * 256 + sl * 8);
        }
        {
            unsigned xs[4] = { x0.x, x0.y, x0.z, x0.w };
            unsigned rv[4] = { r0.x, r0.y, r0.z, r0.w };
            if (c0 >> 31) {
                #pragma unroll
                for (int p = 0; p < 4; ++p) {
                    ao[2*p]   += b2f((unsigned short)(xs[p] & 0xffff)) * b2f((unsigned short)(rv[p] & 0xffff));
                    ao[2*p+1] += b2f((unsigned short)(xs[p] >> 16))    * b2f((unsigned short)(rv[p] >> 16));
                }
            } else {
                #pragma unroll
                for (int p = 0; p < 4; ++p) {
                    ai[2*p]   += b2f((unsigned short)(xs[p] & 0xffff)) * b2f((unsigned short)(rv[p] & 0xffff));
                    ai[2*p+1] += b2f((unsigned short)(xs[p] >> 16))    * b2f((unsigned short)(rv[p] >> 16));
                }
            }
        }
        {
            unsigned xs[4] = { x1.x, x1.y, x1.z, x1.w };
            unsigned rv[4] = { r1.x, r1.y, r1.z, r1.w };
            if (c1 >> 31) {
                #pragma unroll
                for (int p = 0; p < 4; ++p) {
                    ao[2*p]   += b2f((unsigned short)(xs[p] & 0xffff)) * b2f((unsigned short)(rv[p] & 0xffff));
                    ao[2*p+1] += b2f((unsigned short)(xs[p] >> 16))    * b2f((unsigned short)(rv[p] >> 16));
                }
            } else {
                #pragma unroll
                for (int p = 0; p < 4; ++p) {
                    ai[2*p]   += b2f((unsigned short)(xs[p] & 0xffff)) * b2f((unsigned short)(rv[p] & 0xffff));
                    ai[2*p+1] += b2f((unsigned short)(xs[p] >> 16))    * b2f((unsigned short)(rv[p] >> 16));
                }
            }
        }
    }

    // combine halves: every lane ends with the full per-column totals
    #pragma unroll
    for (int j = 0; j < 8; ++j) {
        ai[j] += __shfl_xor(ai[j], 32, 64);
        ao[j] += __shfl_xor(ao[j], 32, 64);
    }

    unsigned ow[4];
    if (h == 0) {
        #pragma unroll
        for (int p = 0; p < 4; ++p)
            ow[p] = (unsigned)f2b(ai[2*p] * nm) | ((unsigned)f2b(ai[2*p+1] * nm) << 16);
        *(uint4*)(sIn + (size_t)v * 256 + sl * 8) = make_uint4(ow[0], ow[1], ow[2], ow[3]);
    } else {
        #pragma unroll
        for (int p = 0; p < 4; ++p)
            ow[p] = (unsigned)f2b(ao[2*p] * nm) | ((unsigned)f2b(ao[2*p+1] * nm) << 16);
        *(uint4*)(sOut + (size_t)v * 256 + sl * 8) = make_uint4(ow[0], ow[1], ow[2], ow[3]);
    }
}

// ---- CONTROL: R8 4-edge pipelined gather -----------------------------------

__global__ __launch_bounds__(256)
void k_agg(const unsigned short* __restrict__ xb, const unsigned short* __restrict__ relb,
           const int* __restrict__ rowptr, const unsigned* __restrict__ erec,
           const float* __restrict__ norm,
           unsigned short* __restrict__ sIn, unsigned short* __restrict__ sOut,
           int N, int D)
{
    const int w = threadIdx.x >> 6, l = threadIdx.x & 63;
    const int v = blockIdx.x * 4 + w;
    if (v >= N) return;
    const int rs = rowptr[v], re = rowptr[v + 1];
    const float nm = norm[v];

    float ai0 = 0, ai1 = 0, ai2 = 0, ai3 = 0;
    float ao0 = 0, ao1 = 0, ao2 = 0, ao3 = 0;

    unsigned c0 = (rs     < re) ? erec[rs]     : 0u;
    unsigned c1 = (rs + 1 < re) ? erec[rs + 1] : 0u;
    unsigned c2 = (rs + 2 < re) ? erec[rs + 2] : 0u;
    unsigned c3 = (rs + 3 < re) ? erec[rs + 3] : 0u;
    int i = rs;
    while (i + 4 <= re) {
        unsigned m0 = (i + 4 < re) ? erec[i + 4] : 0u;
        unsigned m1 = (i + 5 < re) ? erec[i + 5] : 0u;
        unsigned m2 = (i + 6 < re) ? erec[i + 6] : 0u;
        unsigned m3 = (i + 7 < re) ? erec[i + 7] : 0u;
        ushort4 x0 = *(const ushort4*)(xb   + (size_t)(c0 & 0xffff) * D + l * 4);
        ushort4 r0 = *(const ushort4*)(relb + (size_t)((c0 >> 16) & 0x7fff) * D + l * 4);
        ushort4 x1 = *(const ushort4*)(xb   + (size_t)(c1 & 0xffff) * D + l * 4);
        ushort4 r1 = *(const ushort4*)(relb + (size_t)((c1 >> 16) & 0x7fff) * D + l * 4);
        ushort4 x2 = *(const ushort4*)(xb   + (size_t)(c2 & 0xffff) * D + l * 4);
        ushort4 r2 = *(const ushort4*)(relb + (size_t)((c2 >> 16) & 0x7fff) * D + l * 4);
        ushort4 x3 = *(const ushort4*)(xb   + (size_t)(c3 & 0xffff) * D + l * 4);
        ushort4 r3 = *(const ushort4*)(relb + (size_t)((c3 >> 16) & 0x7fff) * D + l * 4);
        float p0, p1, p2, p3;
        p0 = b2f(x0.x)*b2f(r0.x); p1 = b2f(x0.y)*b2f(r0.y);
        p2 = b2f(x0.z)*b2f(r0.z); p3 = b2f(x0.w)*b2f(r0.w);
        if (c0 >> 31) { ao0 += p0; ao1 += p1; ao2 += p2; ao3 += p3; }
        else          { ai0 += p0; ai1 += p1; ai2 += p2; ai3 += p3; }
        p0 = b2f(x1.x)*b2f(r1.x); p1 = b2f(x1.y)*b2f(r1.y);
        p2 = b2f(x1.z)*b2f(r1.z); p3 = b2f(x1.w)*b2f(r1.w);
        if (c1 >> 31) { ao0 += p0; ao1 += p1; ao2 += p2; ao3 += p3; }
        else          { ai0 += p0; ai1 += p1; ai2 += p2; ai3 += p3; }
        p0 = b2f(x2.x)*b2f(r2.x); p1 = b2f(x2.y)*b2f(r2.y);
        p2 = b2f(x2.z)*b2f(r2.z); p3 = b2f(x2.w)*b2f(r2.w);
        if (c2 >> 31) { ao0 += p0; ao1 += p1; ao2 += p2; ao3 += p3; }
        else          { ai0 += p0; ai1 += p1; ai2 += p2; ai3 += p3; }
        p0 = b2f(x3.x)*b2f(r3.x); p1 = b2f(x3.y)*b2f(r3.y);
        p2 = b2f(x3.z)*b2f(r3.z); p3 = b2f(x3.w)*b2f(r3.w);
        if (c3 >> 31) { ao0 += p0; ao1 += p1; ao2 += p2; ao3 += p3; }
        else          { ai0 += p0; ai1 += p1; ai2 += p2; ai3 += p3; }
        c0 = m0; c1 = m1; c2 = m2; c3 = m3; i += 4;
    }
    #pragma unroll
    for (int j = 0; j < 3; ++j) {
        if (i + j < re) {
            unsigned cur = (j == 0) ? c0 : (j == 1) ? c1 : c2;
            ushort4 x0 = *(const ushort4*)(xb   + (size_t)(cur & 0xffff) * D + l * 4);
            ushort4 r0 = *(const ushort4*)(relb + (size_t)((cur >> 16) & 0x7fff) * D + l * 4);
            float p0 = b2f(x0.x)*b2f(r0.x), p1 = b2f(x0.y)*b2f(r0.y);
            float p2 = b2f(x0.z)*b2f(r0.z), p3 = b2f(x0.w)*b2f(r0.w);
            if (cur >> 31) { ao0 += p0; ao1 += p1; ao2 += p2; ao3 += p3; }
            else           { ai0 += p0; ai1 += p1; ai2 += p2; ai3 += p3; }
        }
    }

    ushort4 oi, oo;
    oi.x = f2b(ai0 * nm); oi.y = f2b(ai1 * nm); oi.z = f2b(ai2 * nm); oi.w = f2b(ai3 * nm);
    oo.x = f2b(ao0 * nm); oo.y = f2b(ao1 * nm); oo.z = f2b(ao2 * nm); oo.w = f2b(ao3 * nm);
    *(ushort4*)(sIn  + (size_t)v * D + l * 4) = oi;
    *(ushort4*)(sOut + (size_t)v * D + l * 4) = oo;
}

// ---- EXPERIMENT: 8-wave GEMM, single-B, M-split wave pairs -----------------
// Wave w: cols (w&3)*64, rows 32*(w>>2) .. +32.  512 threads stage one 64x64
// tile in one chunk/thread.  3-deep A prefetch, B loaded in-step (L2-hot).

#define GIT512(S, AtC, AtN, Rw, Rl)                                            \
  do {                                                                         \
    if ((S) + 1 < 12) {                                                        \
      *(uint4*)(&AtN[wo]) = Rw;                                                \
    }                                                                          \
    {                                                                          \
      const int p_ = (S) >> 2, cb_ = (S) & 3;                                  \
      const unsigned short* __restrict__ Wp_ = Wf + (size_t)p_ * 65536;        \
      _Pragma("unroll")                                                        \
      for (int kk_ = 0; kk_ < 2; ++kk_) {                                      \
        const int kg_ = cb_ * 2 + kk_;                                         \
        bf16x8 a_[2], b_[4];                                                   \
        _Pragma("unroll")                                                      \
        for (int m_ = 0; m_ < 2; ++m_) {                                       \
          int rm_ = 32 * wm + 16 * m_ + lr;                                    \
          int ch_ = (kk_ * 4 + lq) ^ (rm_ & 7);                                \
          a_[m_] = *(const bf16x8*)(&AtC[rm_ * 64 + ch_ * 8]);                 \
        }                                                                      \
        _Pragma("unroll")                                                      \
        for (int n_ = 0; n_ < 4; ++n_) {                                       \
          b_[n_] = *(const bf16x8*)(Wp_ + (((kg_ * 16 + (wcol * 4 + n_)) * 64 + l) * 8)); \
        }                                                                      \
        _Pragma("unroll")                                                      \
        for (int m_ = 0; m_ < 2; ++m_) {                                       \
          _Pragma("unroll")                                                    \
          for (int n_ = 0; n_ < 4; ++n_) {                                     \
            acc[m_][n_] = __builtin_amdgcn_mfma_f32_16x16x32_bf16(a_[m_], b_[n_], acc[m_][n_], 0, 0, 0); \
          }                                                                    \
        }                                                                      \
      }                                                                        \
    }                                                                          \
    if ((S) + 3 < 12) {                                                        \
      const int p3_ = ((S) + 3) >> 2, cb3_ = ((S) + 3) & 3;                    \
      const unsigned short* ap_ = (p3_ == 0) ? a0 : ((p3_ == 1) ? a1 : a2);    \
      Rl = *(const uint4*)(ap_ + g + cb3_ * 64);                               \
    }                                                                          \
    asm volatile("s_waitcnt lgkmcnt(0)" ::: "memory");                         \
    __builtin_amdgcn_sched_barrier(0);                                         \
    __builtin_amdgcn_s_barrier();                                              \
    __builtin_amdgcn_sched_barrier(0);                                         \
  } while (0)

__global__ __launch_bounds__(512, 6)
void k_gemm512(const unsigned short* __restrict__ a0,
               const unsigned short* __restrict__ a1,
               const unsigned short* __restrict__ a2,
               const unsigned short* __restrict__ Wf,
               const float* __restrict__ bias,
               const float* __restrict__ resPtr,
               unsigned short* __restrict__ outB,
               int N, int D)
{
    __shared__ unsigned short lds[8192];       // 16 KB: At dbuf / C staging
    unsigned short* At0 = lds;
    unsigned short* At1 = lds + 4096;

    const int t = threadIdx.x;                 // 0..511
    const int rBase = blockIdx.x * 64;
    const int w    = t >> 6;
    const int wcol = w & 3;
    const int wm   = w >> 2;
    const int l  = t & 63;
    const int lr = l & 15;
    const int lq = l >> 4;

    const int rS = t >> 3;                     // 0..63
    const int cS = t & 7;
    const int wo = rS * 64 + ((cS ^ (rS & 7)) * 8);
    const size_t g = (size_t)min(rBase + rS, N - 1) * 256 + cS * 8;

    f32x4 acc[2][4] = {};
    uint4 Ra, Rb, Rc;

    Ra = *(const uint4*)(a0 + g);
    Rb = *(const uint4*)(a0 + g + 64);
    Rc = *(const uint4*)(a0 + g + 128);
    *(uint4*)(&At0[wo]) = Ra;
    asm volatile("s_waitcnt lgkmcnt(0)" ::: "memory");
    __builtin_amdgcn_sched_barrier(0);
    __builtin_amdgcn_s_barrier();
    __builtin_amdgcn_sched_barrier(0);

    GIT512(0,  At0, At1, Rb, Ra);
    GIT512(1,  At1, At0, Rc, Rb);
    GIT512(2,  At0, At1, Ra, Rc);
    GIT512(3,  At1, At0, Rb, Ra);
    GIT512(4,  At0, At1, Rc, Rb);
    GIT512(5,  At1, At0, Ra, Rc);
    GIT512(6,  At0, At1, Rb, Ra);
    GIT512(7,  At1, At0, Rc, Rb);
    GIT512(8,  At0, At1, Ra, Rc);
    GIT512(9,  At1, At0, Rb, Ra);
    GIT512(10, At0, At1, Rc, Rb);
    GIT512(11, At1, At0, Ra, Rc);

    // ---- coalesced epilogue: 64x128 bf16 halves via LDS ----
    const int rb4 = lq * 4;
    const float resv = resPtr[0];
    unsigned short* C = lds;
    #pragma unroll
    for (int half = 0; half < 2; ++half) {
        if ((wcol >> 1) == half) {
            #pragma unroll
            for (int m = 0; m < 2; ++m) {
                #pragma unroll
                for (int i = 0; i < 4; ++i) {
                    int r6 = 32 * wm + 16 * m + rb4 + i;
                    #pragma unroll
                    for (int n = 0; n < 4; ++n) {
                        int cH = (wcol & 1) * 64 + lr + 16 * n;
                        float v = acc[m][n][i] + bias[half * 128 + cH];
                        C[r6 * 128 + cH] = f2b(resv * ftanh(v));
                    }
                }
            }
        }
        __syncthreads();
        #pragma unroll
        for (int ii = 0; ii < 2; ++ii) {
            int g2  = ii * 512 + t;            // 1024 chunks total
            int r   = g2 >> 4;
            int cc  = g2 & 15;
            int row = rBase + r;
            if (row < N) {
                bf16x8 sv = *(const bf16x8*)(&C[r * 128 + cc * 8]);
                const unsigned short* ar = a0 + (size_t)row * D + half * 128 + cc * 8;
                uint4 av = *(const uint4*)ar;
                unsigned aw[4] = { av.x, av.y, av.z, av.w };
                unsigned ow[4];
                #pragma unroll
                for (int p = 0; p < 4; ++p) {
                    float h0 = b2f((unsigned short)(aw[p] & 0xffff)) + b2f((unsigned short)sv[2 * p]);
                    float h1 = b2f((unsigned short)(aw[p] >> 16))    + b2f((unsigned short)sv[2 * p + 1]);
                    ow[p] = (unsigned)f2b(h0) | ((unsigned)f2b(h1) << 16);
                }
                *(uint4*)(outB + (size_t)row * D + half * 128 + cc * 8) =
                    make_uint4(ow[0], ow[1], ow[2], ow[3]);
            }
        }
        __syncthreads();
    }
}

// ---- CONTROL: R8 barrier-pipelined fused GEMM (layer 2 + head) ------------

#define GIT(S, AtC, AtN, Rw0, Rw1, Rl0, Rl1, Bc, Bn)                            \
  do {                                                                          \
    if ((S) + 1 < 12) {                                                         \
      *(uint4*)(&AtN[wo0]) = Rw0;                                               \
      *(uint4*)(&AtN[wo1]) = Rw1;                                               \
    }                                                                           \
    if ((S) + 1 < 12) {                                                         \
      const int pn_ = ((S) + 1) >> 2, cbn_ = ((S) + 1) & 3;                     \
      const unsigned short* __restrict__ Wn_ = Wf + (size_t)pn_ * 65536;        \
      _Pragma("unroll")                                                         \
      for (int kk_ = 0; kk_ < 2; ++kk_) {                                       \
        _Pragma("unroll")                                                       \
        for (int n_ = 0; n_ < 4; ++n_) {                                        \
          Bn[kk_ * 4 + n_] = *(const bf16x8*)(Wn_ +                             \
              ((((cbn_ * 2 + kk_) * 16 + (w * 4 + n_)) * 64 + l) * 8));         \
        }                                                                       \
      }                                                                         \
    }                                                                           \
    {                                                                           \
      const int cb_ = (S) & 3;                                                  \
      _Pragma("unroll")                                                         \
      for (int kk_ = 0; kk_ < 2; ++kk_) {                                       \
        (void)cb_;                                                              \
        bf16x8 a_[4];                                                           \
        _Pragma("unroll")                                                       \
        for (int m_ = 0; m_ < 4; ++m_) {                                        \
          int rm_ = 16 * m_ + lr;                                               \
          int ch_ = (kk_ * 4 + lq) ^ (rm_ & 7);                                 \
          a_[m_] = *(const bf16x8*)(&AtC[rm_ * 64 + ch_ * 8]);                  \
        }                                                                       \
        _Pragma("unroll")                                                       \
        for (int m_ = 0; m_ < 4; ++m_) {                                        \
          _Pragma("unroll")                                                     \
          for (int n_ = 0; n_ < 4; ++n_) {                                      \
            acc[m_][n_] = __builtin_amdgcn_mfma_f32_16x16x32_bf16(a_[m_], Bc[kk_ * 4 + n_], acc[m_][n_], 0, 0, 0); \
          }                                                                     \
        }                                                                       \
      }                                                                         \
    }                                                                           \
    if ((S) + 3 < 12) {                                                         \
      const int p3_ = ((S) + 3) >> 2, cb3_ = ((S) + 3) & 3;                     \
      const unsigned short* ap_ = (p3_ == 0) ? a0 : ((p3_ == 1) ? a1 : a2);     \
      Rl0 = *(const uint4*)(ap_ + g0 + cb3_ * 64);                              \
      Rl1 = *(const uint4*)(ap_ + g1 + cb3_ * 64);                              \
    }                                                                           \
    asm volatile("s_waitcnt lgkmcnt(0)" ::: "memory");                          \
    __builtin_amdgcn_sched_barrier(0);                                          \
    __builtin_amdgcn_s_barrier();                                               \
    __builtin_amdgcn_sched_barrier(0);                                          \
  } while (0)

template <bool HEAD>
__global__ __launch_bounds__(256, 2)
void k_gemm(const unsigned short* __restrict__ a0,
            const unsigned short* __restrict__ a1,
            const unsigned short* __restrict__ a2,
            const unsigned short* __restrict__ Wf,    // frag layout, 3*65536
            const float* __restrict__ bias,
            const float* __restrict__ resPtr,
            const unsigned short* __restrict__ WfMu,  // frag layout (HEAD)
            const float* __restrict__ mub,            // [256] (HEAD)
            float* __restrict__ outF,                 // [N,256] f32 (HEAD)
            unsigned short* __restrict__ outB,        // [N,256] bf16 (!HEAD)
            int N, int D)
{
    __shared__ unsigned short lds[HEAD ? 16384 : 8192];
    unsigned short* At0 = lds;
    unsigned short* At1 = lds + 4096;

    const int t = threadIdx.x;
    const int rBase = blockIdx.x * 64;

    const int w  = t >> 6;
    const int l  = t & 63;
    const int lr = l & 15;
    const int lq = l >> 4;

    const int rS0 = t >> 3;
    const int rS1 = rS0 + 32;
    const int cS  = t & 7;
    const int wo0 = rS0 * 64 + ((cS ^ (rS0 & 7)) * 8);
    const int wo1 = rS1 * 64 + ((cS ^ (rS1 & 7)) * 8);
    const size_t g0 = (size_t)min(rBase + rS0, N - 1) * D + cS * 8;
    const size_t g1 = (size_t)min(rBase + rS1, N - 1) * D + cS * 8;

    f32x4 acc[4][4] = {};
    uint4 Ra0, Ra1, Rb0, Rb1, Rc0, Rc1;
    bf16x8 B0[8], B1[8];

    Ra0 = *(const uint4*)(a0 + g0);
    Ra1 = *(const uint4*)(a0 + g1);
    Rb0 = *(const uint4*)(a0 + g0 + 64);
    Rb1 = *(const uint4*)(a0 + g1 + 64);
    Rc0 = *(const uint4*)(a0 + g0 + 128);
    Rc1 = *(const uint4*)(a0 + g1 + 128);
    #pragma unroll
    for (int kk = 0; kk < 2; ++kk) {
        #pragma unroll
        for (int n = 0; n < 4; ++n)
            B0[kk * 4 + n] = *(const bf16x8*)(Wf + (((kk * 16 + (w * 4 + n)) * 64 + l) * 8));
    }
    *(uint4*)(&At0[wo0]) = Ra0;
    *(uint4*)(&At0[wo1]) = Ra1;
    asm volatile("s_waitcnt lgkmcnt(0)" ::: "memory");
    __builtin_amdgcn_sched_barrier(0);
    __builtin_amdgcn_s_barrier();
    __builtin_amdgcn_sched_barrier(0);

    GIT(0,  At0, At1, Rb0, Rb1, Ra0, Ra1, B0, B1);
    GIT(1,  At1, At0, Rc0, Rc1, Rb0, Rb1, B1, B0);
    GIT(2,  At0, At1, Ra0, Ra1, Rc0, Rc1, B0, B1);
    GIT(3,  At1, At0, Rb0, Rb1, Ra0, Ra1, B1, B0);
    GIT(4,  At0, At1, Rc0, Rc1, Rb0, Rb1, B0, B1);
    GIT(5,  At1, At0, Ra0, Ra1, Rc0, Rc1, B1, B0);
    GIT(6,  At0, At1, Rb0, Rb1, Ra0, Ra1, B0, B1);
    GIT(7,  At1, At0, Rc0, Rc1, Rb0, Rb1, B1, B0);
    GIT(8,  At0, At1, Ra0, Ra1, Rc0, Rc1, B0, B1);
    GIT(9,  At1, At0, Rb0, Rb1, Ra0, Ra1, B1, B0);
    GIT(10, At0, At1, Rc0, Rc1, Rb0, Rb1, B0, B1);
    GIT(11, At1, At0, Ra0, Ra1, Rc0, Rc1, B1, B0);

    const int rb4 = lq * 4;
    const float resv = resPtr[0];

    if (!HEAD) {
        unsigned short* C = lds;
        #pragma unroll
        for (int half = 0; half < 2; ++half) {
            if ((w >> 1) == half) {
                #pragma unroll
                for (int m = 0; m < 4; ++m) {
                    #pragma unroll
                    for (int i = 0; i < 4; ++i) {
                        int r6 = 16 * m + rb4 + i;
                        #pragma unroll
                        for (int n = 0; n < 4; ++n) {
                            int cH = (w & 1) * 64 + lr + 16 * n;
                            float v = acc[m][n][i] + bias[half * 128 + cH];
                            C[r6 * 128 + cH] = f2b(resv * ftanh(v));
                        }
                    }
                }
            }
            __syncthreads();
            #pragma unroll
            for (int ii = 0; ii < 4; ++ii) {
                int g   = ii * 256 + t;
                int r   = g >> 4;
                int cc  = g & 15;
                int row = rBase + r;
                if (row < N) {
                    bf16x8 sv = *(const bf16x8*)(&C[r * 128 + cc * 8]);
                    const unsigned short* ar = a0 + (size_t)row * D + half * 128 + cc * 8;
                    uint4 av = *(const uint4*)ar;
                    unsigned aw[4] = { av.x, av.y, av.z, av.w };
                    unsigned ow[4];
                    #pragma unroll
                    for (int p = 0; p < 4; ++p) {
                        float h0 = b2f((unsigned short)(aw[p] & 0xffff)) + b2f((unsigned short)sv[2 * p]);
                        float h1 = b2f((unsigned short)(aw[p] >> 16))    + b2f((unsigned short)sv[2 * p + 1]);
                        ow[p] = (unsigned)f2b(h0) | ((unsigned)f2b(h1) << 16);
                    }
                    *(uint4*)(outB + (size_t)row * D + half * 128 + cc * 8) =
                        make_uint4(ow[0], ow[1], ow[2], ow[3]);
                }
            }
            __syncthreads();
        }
    } else {
        #pragma unroll
        for (int m = 0; m < 4; ++m) {
            #pragma unroll
            for (int i = 0; i < 4; ++i) {
                int row = rBase + 16 * m + rb4 + i;
                if (row < N) {
                    size_t base = (size_t)row * D + w * 64 + lr;
                    int r6 = 16 * m + rb4 + i;
                    #pragma unroll
                    for (int n = 0; n < 4; ++n) {
                        int   c = w * 64 + lr + 16 * n;
                        float v = acc[m][n][i] + bias[c];
                        float h = b2f(a0[base + 16 * n]) + resv * ftanh(v);
                        lds[r6 * 256 + (c ^ ((r6 & 7) << 3))] = f2b(h);
                    }
                }
            }
        }
        __syncthreads();
        #pragma unroll
        for (int m = 0; m < 4; ++m) {
            #pragma unroll
            for (int n = 0; n < 4; ++n)
                acc[m][n] = (f32x4){0.f, 0.f, 0.f, 0.f};
        }

        #pragma unroll
        for (int s2 = 0; s2 < 4; ++s2) {
            #pragma unroll
            for (int kk = 0; kk < 2; ++kk) {
                const int kg = s2 * 2 + kk;
                bf16x8 a_[4], b_[4];
                #pragma unroll
                for (int m = 0; m < 4; ++m) {
                    int rm = 16 * m + lr;
                    int ch = (s2 * 8 + kk * 4 + lq) ^ (rm & 7);
                    a_[m] = *(const bf16x8*)(&lds[rm * 256 + ch * 8]);
                }
                #pragma unroll
                for (int n = 0; n < 4; ++n)
                    b_[n] = *(const bf16x8*)(WfMu + (((kg * 16 + (w * 4 + n)) * 64 + l) * 8));
                #pragma unroll
                for (int m = 0; m < 4; ++m) {
                    #pragma unroll
                    for (int n = 0; n < 4; ++n)
                        acc[m][n] = __builtin_amdgcn_mfma_f32_16x16x32_bf16(a_[m], b_[n], acc[m][n], 0, 0, 0);
                }
            }
        }

        __syncthreads();
        float* Cf = (float*)lds;
        #pragma unroll
        for (int half = 0; half < 2; ++half) {
            if ((w >> 1) == half) {
                #pragma unroll
                for (int m = 0; m < 4; ++m) {
                    #pragma unroll
                    for (int i = 0; i < 4; ++i) {
                        int r6 = 16 * m + rb4 + i;
                        #pragma unroll
                        for (int n = 0; n < 4; ++n) {
                            int cH = (w & 1) * 64 + lr + 16 * n;
                            Cf[r6 * 128 + cH] = acc[m][n][i] + mub[half * 128 + cH];
                        }
                    }
                }
            }
            __syncthreads();
            #pragma unroll
            for (int ii = 0; ii < 8; ++ii) {
                int g   = ii * 256 + t;
                int r   = g >> 5;
                int cc  = g & 31;
                int row = rBase + r;
                if (row < N) {
                    *(float4*)(outF + (size_t)row * D + half * 128 + cc * 4) =
                        *(const float4*)(&Cf[r * 128 + cc * 4]);
                }
            }
            __syncthreads();
        }
    }
}

// ---------------------------------------------------------------------------

extern "C" void kernel_launch(void* const* d_in, const int* in_sizes, int n_in,
                              void* d_out, int out_size, void* d_ws, size_t ws_size,
                              hipStream_t stream)
{
    const float* emb  = (const float*)d_in[0];
    const int*   ei   = (const int*)  d_in[1];
    const int*   et   = (const int*)  d_in[2];
    const float* rel1 = (const float*)d_in[3];
    const float* Wi1  = (const float*)d_in[4];
    const float* Wo1  = (const float*)d_in[5];
    const float* Wl1  = (const float*)d_in[6];
    const float* b1   = (const float*)d_in[7];
    const float* rel2 = (const float*)d_in[8];
    const float* Wi2  = (const float*)d_in[9];
    const float* Wo2  = (const float*)d_in[10];
    const float* Wl2  = (const float*)d_in[11];
    const float* b2   = (const float*)d_in[12];
    const float* res  = (const float*)d_in[13];
    const float* muw  = (const float*)d_in[14];
    const float* mub  = (const float*)d_in[15];

    const int D = in_sizes[7];          // 256
    const int N = in_sizes[0] / D;      // 50000
    const int E = in_sizes[2];          // 320000
    const int R = in_sizes[3] / D;      // 400
    const int halfE = E / 2;
    const int* srcA = ei;
    const int* dstA = ei + E;
    const size_t DD = (size_t)D * D;

    char* ws = (char*)d_ws;
    size_t off = 0;
    auto alloc = [&](size_t bytes) -> char* {
        char* p = ws + off; off += (bytes + 255) & ~(size_t)255; return p;
    };
    const int nb1 = (N + 255) / 256;

    float*          norm   = (float*)          alloc((size_t)N * 4);
    int*            cnt    = (int*)            alloc((size_t)N * 4);
    int*            rowptr = (int*)            alloc((size_t)(N + 1) * 4);
    int*            cursor = (int*)            alloc((size_t)N * 4);
    int*            part   = (int*)            alloc((size_t)N * 4);
    int*            bsum   = (int*)            alloc(1024);
    unsigned*       erec   = (unsigned*)       alloc((size_t)E * 4);
    unsigned short* xb     = (unsigned short*) alloc((size_t)N * D * 2);
    unsigned short* h1b    = (unsigned short*) alloc((size_t)N * D * 2);
    unsigned short* sIn    = (unsigned short*) alloc((size_t)N * D * 2);
    unsigned short* sOut   = (unsigned short*) alloc((size_t)N * D * 2);
    unsigned short* r1b    = (unsigned short*) alloc((size_t)R * D * 2);
    unsigned short* r2b    = (unsigned short*) alloc((size_t)R * D * 2);
    unsigned short* fAll   = (unsigned short*) alloc(7 * DD * 2);
    if (off > ws_size) return;

    unsigned short* fW1 = fAll;            // [Wl1, Wi1, Wo1]
    unsigned short* fW2 = fAll + 3 * DD;   // [Wl2, Wi2, Wo2]
    unsigned short* fMu = fAll + 6 * DD;

    // --- CSR + norm ---
    hipMemsetAsync(cnt, 0, (size_t)N * 4, stream);
    k_hist   <<<(E + 255) / 256, 256, 0, stream>>>(dstA, cnt, E);
    k_norm   <<<nb1, 256, 0, stream>>>(cnt, norm, N);
    k_scan1  <<<nb1, 256, 0, stream>>>(cnt, part, bsum, N);
    k_scan2  <<<1,   256, 0, stream>>>(bsum, nb1);
    k_scan3  <<<nb1, 256, 0, stream>>>(part, bsum, rowptr, cursor, N, E);
    k_scatter<<<(E + 255) / 256, 256, 0, stream>>>(srcA, dstA, et, cursor, erec, E, halfE);

    // --- dtype prep ---
    long nd4 = (long)N * D / 4, rd4 = (long)R * D / 4;
    long tot4 = nd4 + 2 * rd4;
    k_cvt3<<<(int)((tot4 + 255) / 256), 256, 0, stream>>>(
        emb, xb, nd4, rel1, r1b, rd4, rel2, r2b, rd4);
    k_wfrag7<<<(int)(7 * DD / 256), 256, 0, stream>>>(
        Wl1, Wi1, Wo1, Wl2, Wi2, Wo2, muw, fAll);

    const int AB = (N + 3) / 4;
    const int NB = (N + 63) / 64;

    // --- layer 1 (EXPERIMENT: k_agg2 + k_gemm512) ---
    k_agg2<<<AB, 256, 0, stream>>>(xb, r1b, rowptr, erec, norm, sIn, sOut, N, D);
    k_gemm512<<<NB, 512, 0, stream>>>(xb, sIn, sOut, fW1, b1, res, h1b, N, D);

    // --- layer 2 + head (CONTROL: R8) ---
    k_agg<<<AB, 256, 0, stream>>>(h1b, r2b, rowptr, erec, norm, sIn, sOut, N, D);
    k_gemm<true><<<NB, 256, 0, stream>>>(h1b, sIn, sOut, fW2, b2, res,
                                         fMu, mub, (float*)d_out, nullptr, N, D);
}

// Round 13
// 232.453 us; speedup vs baseline: 1.0756x; 1.0568x over previous
//
#include <hip/hip_runtime.h>
#include <hip/hip_bf16.h>
#include <cstdint>
#include <cstddef>

// ---------------------------------------------------------------------------
// MGCN (2-layer relational GCN + linear head).
//
//   s_in[v]  = norm[v] * sum_{first-half edges,  dst=v} x[src]*rel[ty]
//   s_out[v] = norm[v] * sum_{second-half edges, dst=v} x[src]*rel[ty]
//   h        = x + res * tanh( x@W_loop + s_in@W_in + s_out@W_out + b )
//   out      = h2 @ mu_w + mu_b     (fused into layer-2 kernel)
//
// NEW: s_in/s_out stored as fp8 e4m3 (half the intermediate HBM traffic);
// the s-part of the GEMM uses mfma_f32_16x16x32_fp8_fp8 with fp8-packed
// W_in/W_out fragment tables.  x-part and head remain bf16.
// ---------------------------------------------------------------------------

typedef short bf16x8 __attribute__((ext_vector_type(8)));
typedef float f32x4  __attribute__((ext_vector_type(4)));

__device__ __forceinline__ float b2f(unsigned short u) {
    union { unsigned u32; float f; } c; c.u32 = ((unsigned)u) << 16; return c.f;
}
__device__ __forceinline__ unsigned short f2b(float f) {
    union { float f; unsigned u; } c; c.f = f;
    unsigned r = c.u + 0x7FFFu + ((c.u >> 16) & 1u);   // RNE
    return (unsigned short)(r >> 16);
}
__device__ __forceinline__ float ftanh(float x) {
    float e = __expf(2.0f * x);
    return 1.0f - __fdividef(2.0f, e + 1.0f);
}

// f32 -> fp8 e4m3fn (OCP), RNE, saturating.  Software: deterministic.
__device__ __forceinline__ unsigned char f2e4m3(float f) {
    unsigned u = __float_as_uint(f);
    unsigned s = (u >> 24) & 0x80u;
    unsigned a = u & 0x7fffffffu;
    if (a >= 0x43e00000u) return (unsigned char)(s | 0x7eu);      // >=448 -> max
    if (a < 0x3c800000u) {                                        // < 2^-6: subnormal
        float m = __uint_as_float(a) * 512.0f;                    // / 2^-9
        int q = (int)rintf(m);                                    // 0..8
        if (q == 8) return (unsigned char)(s | 0x08u);
        return (unsigned char)(s | (unsigned)q);
    }
    unsigned m = a & 0x7fffffu;
    unsigned e = a >> 23;
    unsigned r = m + 0x7ffffu + ((m >> 20) & 1u);
    if (r >= 0x800000u) { e += 1; r -= 0x800000u; }
    if (e > 127u + 8u) return (unsigned char)(s | 0x7eu);
    return (unsigned char)(s | ((e - 127u + 7u) << 3) | (r >> 20));
}

// ---- CSR construction ------------------------------------------------------

__global__ void k_hist(const int* __restrict__ dst, int* __restrict__ cnt, int E) {
    int i = blockIdx.x * blockDim.x + threadIdx.x;
    if (i < E) atomicAdd(&cnt[dst[i]], 1);
}

__global__ void k_norm(const int* __restrict__ cnt, float* __restrict__ norm, int N) {
    int i = blockIdx.x * blockDim.x + threadIdx.x;
    if (i < N) norm[i] = 1.0f / fmaxf((float)cnt[i], 1.0f);
}

__global__ void k_scan1(const int* __restrict__ cnt, int* __restrict__ part,
                        int* __restrict__ bsum, int N) {
    __shared__ int s[256];
    int i = blockIdx.x * 256 + threadIdx.x;
    int v = (i < N) ? cnt[i] : 0;
    s[threadIdx.x] = v; __syncthreads();
    #pragma unroll
    for (int o = 1; o < 256; o <<= 1) {
        int t = (threadIdx.x >= o) ? s[threadIdx.x - o] : 0;
        __syncthreads();
        s[threadIdx.x] += t;
        __syncthreads();
    }
    if (i < N) part[i] = s[threadIdx.x] - v;
    if (threadIdx.x == 255) bsum[blockIdx.x] = s[255];
}

__global__ void k_scan2(int* __restrict__ bsum, int nb) {
    __shared__ int s[256];
    int v = (threadIdx.x < nb) ? bsum[threadIdx.x] : 0;
    s[threadIdx.x] = v; __syncthreads();
    #pragma unroll
    for (int o = 1; o < 256; o <<= 1) {
        int t = (threadIdx.x >= o) ? s[threadIdx.x - o] : 0;
        __syncthreads();
        s[threadIdx.x] += t;
        __syncthreads();
    }
    if (threadIdx.x < nb) bsum[threadIdx.x] = s[threadIdx.x] - v;
}

__global__ void k_scan3(const int* __restrict__ part, const int* __restrict__ bsum,
                        int* __restrict__ rowptr, int* __restrict__ cursor, int N, int E) {
    int i = blockIdx.x * 256 + threadIdx.x;
    if (i < N) {
        int r = part[i] + bsum[blockIdx.x];
        rowptr[i] = r; cursor[i] = r;
    }
    if (i == 0) rowptr[N] = E;
}

__global__ void k_scatter(const int* __restrict__ src, const int* __restrict__ dst,
                          const int* __restrict__ et, int* __restrict__ cursor,
                          unsigned* __restrict__ erec, int E, int halfE) {
    int e = blockIdx.x * blockDim.x + threadIdx.x;
    if (e < E) {
        int d = dst[e];
        int pos = atomicAdd(&cursor[d], 1);
        unsigned rec = (unsigned)src[e] | ((unsigned)et[e] << 16)
                     | ((e >= halfE) ? 0x80000000u : 0u);
        erec[pos] = rec;
    }
}

// ---- dtype prep ------------------------------------------------------------

__global__ void k_cvt3(const float* __restrict__ s0, unsigned short* __restrict__ d0, long n0,
                       const float* __restrict__ s1, unsigned short* __restrict__ d1, long n1,
                       const float* __restrict__ s2, unsigned short* __restrict__ d2, long n2) {
    long i = (long)blockIdx.x * blockDim.x + threadIdx.x;
    const float* s; unsigned short* d; long j = i;
    if (j < n0) { s = s0; d = d0; }
    else {
        j -= n0;
        if (j < n1) { s = s1; d = d1; }
        else { j -= n1; if (j >= n2) return; s = s2; d = d2; }
    }
    float4 v = ((const float4*)s)[j];
    ushort4 o;
    o.x = f2b(v.x); o.y = f2b(v.y); o.z = f2b(v.z); o.w = f2b(v.w);
    ((ushort4*)d)[j] = o;
}

// bf16 fragment tables: W_loop1, W_loop2, mu_w
// out[mi][((kg*16+nn)*64 + l)*8 + j] = W[kg*32 + (l>>4)*8 + j][nn*16 + (l&15)]
__global__ void k_wfrag3(const float* __restrict__ w0, const float* __restrict__ w1,
                         const float* __restrict__ w2, unsigned short* __restrict__ out) {
    int o = blockIdx.x * 256 + threadIdx.x;      // grid = 3*65536/256
    int mi = o >> 16;
    int r  = o & 65535;
    const float* W = (mi == 0) ? w0 : (mi == 1) ? w1 : w2;
    int j  = r & 7;
    int l  = (r >> 3) & 63;
    int nn = (r >> 9) & 15;
    int kg = r >> 13;
    int k = kg * 32 + (l >> 4) * 8 + j;
    int n = nn * 16 + (l & 15);
    out[o] = f2b(W[k * 256 + n]);
}

// fp8 fragment tables: W_in1, W_out1, W_in2, W_out2 (8-byte frags)
__global__ void k_wfrag8(const float* __restrict__ w0, const float* __restrict__ w1,
                         const float* __restrict__ w2, const float* __restrict__ w3,
                         unsigned char* __restrict__ out) {
    int o = (blockIdx.x * 256 + threadIdx.x) * 4;    // grid = 4*65536/1024
    int mi = o >> 16;
    int r  = o & 65535;
    const float* W = (mi == 0) ? w0 : (mi == 1) ? w1 : (mi == 2) ? w2 : w3;
    int j0 = r & 7;                 // 0 or 4
    int l  = (r >> 3) & 63;
    int nn = (r >> 9) & 15;
    int kg = r >> 13;
    int n  = nn * 16 + (l & 15);
    int kb = kg * 32 + (l >> 4) * 8 + j0;
    unsigned b0 = f2e4m3(W[(kb + 0) * 256 + n]);
    unsigned b1 = f2e4m3(W[(kb + 1) * 256 + n]);
    unsigned b2 = f2e4m3(W[(kb + 2) * 256 + n]);
    unsigned b3 = f2e4m3(W[(kb + 3) * 256 + n]);
    *(unsigned*)(out + o) = b0 | (b1 << 8) | (b2 << 16) | (b3 << 24);
}

// ---- CSR gather aggregation (no atomics), 4-edge pipeline, fp8 output -----

__global__ __launch_bounds__(256)
void k_agg(const unsigned short* __restrict__ xb, const unsigned short* __restrict__ relb,
           const int* __restrict__ rowptr, const unsigned* __restrict__ erec,
           const float* __restrict__ norm,
           unsigned char* __restrict__ sIn8, unsigned char* __restrict__ sOut8,
           int N, int D)
{
    const int w = threadIdx.x >> 6, l = threadIdx.x & 63;
    const int v = blockIdx.x * 4 + w;
    if (v >= N) return;
    const int rs = rowptr[v], re = rowptr[v + 1];
    const float nm = norm[v];

    float ai0 = 0, ai1 = 0, ai2 = 0, ai3 = 0;
    float ao0 = 0, ao1 = 0, ao2 = 0, ao3 = 0;

    unsigned c0 = (rs     < re) ? erec[rs]     : 0u;
    unsigned c1 = (rs + 1 < re) ? erec[rs + 1] : 0u;
    unsigned c2 = (rs + 2 < re) ? erec[rs + 2] : 0u;
    unsigned c3 = (rs + 3 < re) ? erec[rs + 3] : 0u;
    int i = rs;
    while (i + 4 <= re) {
        unsigned m0 = (i + 4 < re) ? erec[i + 4] : 0u;
        unsigned m1 = (i + 5 < re) ? erec[i + 5] : 0u;
        unsigned m2 = (i + 6 < re) ? erec[i + 6] : 0u;
        unsigned m3 = (i + 7 < re) ? erec[i + 7] : 0u;
        ushort4 x0 = *(const ushort4*)(xb   + (size_t)(c0 & 0xffff) * D + l * 4);
        ushort4 r0 = *(const ushort4*)(relb + (size_t)((c0 >> 16) & 0x7fff) * D + l * 4);
        ushort4 x1 = *(const ushort4*)(xb   + (size_t)(c1 & 0xffff) * D + l * 4);
        ushort4 r1 = *(const ushort4*)(relb + (size_t)((c1 >> 16) & 0x7fff) * D + l * 4);
        ushort4 x2 = *(const ushort4*)(xb   + (size_t)(c2 & 0xffff) * D + l * 4);
        ushort4 r2 = *(const ushort4*)(relb + (size_t)((c2 >> 16) & 0x7fff) * D + l * 4);
        ushort4 x3 = *(const ushort4*)(xb   + (size_t)(c3 & 0xffff) * D + l * 4);
        ushort4 r3 = *(const ushort4*)(relb + (size_t)((c3 >> 16) & 0x7fff) * D + l * 4);
        float p0, p1, p2, p3;
        p0 = b2f(x0.x)*b2f(r0.x); p1 = b2f(x0.y)*b2f(r0.y);
        p2 = b2f(x0.z)*b2f(r0.z); p3 = b2f(x0.w)*b2f(r0.w);
        if (c0 >> 31) { ao0 += p0; ao1 += p1; ao2 += p2; ao3 += p3; }
        else          { ai0 += p0; ai1 += p1; ai2 += p2; ai3 += p3; }
        p0 = b2f(x1.x)*b2f(r1.x); p1 = b2f(x1.y)*b2f(r1.y);
        p2 = b2f(x1.z)*b2f(r1.z); p3 = b2f(x1.w)*b2f(r1.w);
        if (c1 >> 31) { ao0 += p0; ao1 += p1; ao2 += p2; ao3 += p3; }
        else          { ai0 += p0; ai1 += p1; ai2 += p2; ai3 += p3; }
        p0 = b2f(x2.x)*b2f(r2.x); p1 = b2f(x2.y)*b2f(r2.y);
        p2 = b2f(x2.z)*b2f(r2.z); p3 = b2f(x2.w)*b2f(r2.w);
        if (c2 >> 31) { ao0 += p0; ao1 += p1; ao2 += p2; ao3 += p3; }
        else          { ai0 += p0; ai1 += p1; ai2 += p2; ai3 += p3; }
        p0 = b2f(x3.x)*b2f(r3.x); p1 = b2f(x3.y)*b2f(r3.y);
        p2 = b2f(x3.z)*b2f(r3.z); p3 = b2f(x3.w)*b2f(r3.w);
        if (c3 >> 31) { ao0 += p0; ao1 += p1; ao2 += p2; ao3 += p3; }
        else          { ai0 += p0; ai1 += p1; ai2 += p2; ai3 += p3; }
        c0 = m0; c1 = m1; c2 = m2; c3 = m3; i += 4;
    }
    #pragma unroll
    for (int j = 0; j < 3; ++j) {
        if (i + j < re) {
            unsigned cur = (j == 0) ? c0 : (j == 1) ? c1 : c2;
            ushort4 x0 = *(const ushort4*)(xb   + (size_t)(cur & 0xffff) * D + l * 4);
            ushort4 r0 = *(const ushort4*)(relb + (size_t)((cur >> 16) & 0x7fff) * D + l * 4);
            float p0 = b2f(x0.x)*b2f(r0.x), p1 = b2f(x0.y)*b2f(r0.y);
            float p2 = b2f(x0.z)*b2f(r0.z), p3 = b2f(x0.w)*b2f(r0.w);
            if (cur >> 31) { ao0 += p0; ao1 += p1; ao2 += p2; ao3 += p3; }
            else           { ai0 += p0; ai1 += p1; ai2 += p2; ai3 += p3; }
        }
    }

    unsigned pi = (unsigned)f2e4m3(ai0 * nm)        | ((unsigned)f2e4m3(ai1 * nm) << 8)
                | ((unsigned)f2e4m3(ai2 * nm) << 16) | ((unsigned)f2e4m3(ai3 * nm) << 24);
    unsigned po = (unsigned)f2e4m3(ao0 * nm)        | ((unsigned)f2e4m3(ao1 * nm) << 8)
                | ((unsigned)f2e4m3(ao2 * nm) << 16) | ((unsigned)f2e4m3(ao3 * nm) << 24);
    *(unsigned*)(sIn8  + (size_t)v * 256 + l * 4) = pi;
    *(unsigned*)(sOut8 + (size_t)v * 256 + l * 4) = po;
}

// ---- hybrid bf16/fp8 GEMM --------------------------------------------------
// Steps 0-3: x (bf16) @ W_loop.  Steps 4-7: sIn (fp8) @ W_in.
// Steps 8-11: sOut (fp8) @ W_out.  3-deep A prefetch, 1-ahead B prefetch,
// one fenced s_barrier per step, vmem never drained.

#define FB  do { asm volatile("s_waitcnt lgkmcnt(0)" ::: "memory");             \
                 __builtin_amdgcn_sched_barrier(0);                             \
                 __builtin_amdgcn_s_barrier();                                  \
                 __builtin_amdgcn_sched_barrier(0); } while (0)

#define WRX(AtN, R0, R1) do { *(uint4*)(&(AtN)[wo0]) = R0;                      \
                              *(uint4*)(&(AtN)[wo1]) = R1; } while (0)
#define WR8(AtN, R0)     do { *(uint4*)(((char*)(AtN)) + wf8b) = R0; } while (0)
#define LDX(R0, R1, CB)  do { R0 = *(const uint4*)(a0 + g0 + (CB)*64);          \
                              R1 = *(const uint4*)(a0 + g1 + (CB)*64); } while (0)
#define LD8(R0, SRC, CB) do { R0 = *(const uint4*)((SRC) + gf8 + (CB)*64); } while (0)

#define PBX(Bn, CB)                                                             \
  do { _Pragma("unroll")                                                        \
       for (int kk_ = 0; kk_ < 2; ++kk_) {                                      \
         _Pragma("unroll")                                                      \
         for (int n_ = 0; n_ < 4; ++n_)                                         \
           Bn[kk_*4+n_] = *(const bf16x8*)(WfL +                                \
               ((((CB)*2+kk_)*16 + (w*4+n_))*64 + l)*8);                        \
       } } while (0)

#define PB8(Bn, TBL, CB)                                                        \
  do { _Pragma("unroll")                                                        \
       for (int kk_ = 0; kk_ < 2; ++kk_) {                                      \
         _Pragma("unroll")                                                      \
         for (int n_ = 0; n_ < 4; ++n_)                                         \
           Bn[kk_*4+n_] = *(const long long*)((TBL) +                           \
               ((((CB)*2+kk_)*16 + (w*4+n_))*64 + l)*8);                        \
       } } while (0)

#define MMX(AtC, Bc)                                                            \
  do { _Pragma("unroll")                                                        \
       for (int kk_ = 0; kk_ < 2; ++kk_) {                                      \
         bf16x8 a_[4];                                                          \
         _Pragma("unroll")                                                      \
         for (int m_ = 0; m_ < 4; ++m_) {                                       \
           int rm_ = 16*m_ + lr; int ch_ = (kk_*4+lq) ^ (rm_ & 7);              \
           a_[m_] = *(const bf16x8*)(&(AtC)[rm_*64 + ch_*8]);                   \
         }                                                                      \
         _Pragma("unroll")                                                      \
         for (int m_ = 0; m_ < 4; ++m_) {                                       \
           _Pragma("unroll")                                                    \
           for (int n_ = 0; n_ < 4; ++n_)                                       \
             acc[m_][n_] = __builtin_amdgcn_mfma_f32_16x16x32_bf16(             \
                 a_[m_], Bc[kk_*4+n_], acc[m_][n_], 0, 0, 0);                   \
         } } } while (0)

#define MM8(AtC, Bc)                                                            \
  do { const char* A8_ = (const char*)(AtC);                                    \
       _Pragma("unroll")                                                        \
       for (int kk_ = 0; kk_ < 2; ++kk_) {                                      \
         long long a_[4];                                                       \
         _Pragma("unroll")                                                      \
         for (int m_ = 0; m_ < 4; ++m_) {                                       \
           int rm_ = 16*m_ + lr; int ch_ = (kk_*4+lq) ^ (rm_ & 6);              \
           a_[m_] = *(const long long*)(A8_ + rm_*64 + ch_*8);                  \
         }                                                                      \
         _Pragma("unroll")                                                      \
         for (int m_ = 0; m_ < 4; ++m_) {                                       \
           _Pragma("unroll")                                                    \
           for (int n_ = 0; n_ < 4; ++n_)                                       \
             acc[m_][n_] = __builtin_amdgcn_mfma_f32_16x16x32_fp8_fp8(          \
                 a_[m_], Bc[kk_*4+n_], acc[m_][n_], 0, 0, 0);                   \
         } } } while (0)

template <bool HEAD>
__global__ __launch_bounds__(256, 2)
void k_gemm(const unsigned short* __restrict__ a0,     // [N,256] bf16 x / h1
            const unsigned char*  __restrict__ s8i,    // [N,256] fp8 sIn
            const unsigned char*  __restrict__ s8o,    // [N,256] fp8 sOut
            const unsigned short* __restrict__ WfL,    // bf16 frag table (W_loop)
            const unsigned char*  __restrict__ W8I,    // fp8 frag table (W_in)
            const unsigned char*  __restrict__ W8O,    // fp8 frag table (W_out)
            const float* __restrict__ bias,
            const float* __restrict__ resPtr,
            const unsigned short* __restrict__ WfMu,   // bf16 frag table (HEAD)
            const float* __restrict__ mub,             // (HEAD)
            float* __restrict__ outF,                  // (HEAD)
            unsigned short* __restrict__ outB,         // (!HEAD)
            int N, int D)
{
    __shared__ unsigned short lds[HEAD ? 16384 : 8192];
    unsigned short* At0 = lds;
    unsigned short* At1 = lds + 4096;

    const int t = threadIdx.x;
    const int rBase = blockIdx.x * 64;

    const int w  = t >> 6;
    const int l  = t & 63;
    const int lr = l & 15;
    const int lq = l >> 4;

    // bf16 staging geometry (two 16B chunks / thread)
    const int rS0 = t >> 3;
    const int rS1 = rS0 + 32;
    const int cS  = t & 7;
    const int wo0 = rS0 * 64 + ((cS ^ (rS0 & 7)) * 8);
    const int wo1 = rS1 * 64 + ((cS ^ (rS1 & 7)) * 8);
    const size_t g0 = (size_t)min(rBase + rS0, N - 1) * 256 + cS * 8;
    const size_t g1 = (size_t)min(rBase + rS1, N - 1) * 256 + cS * 8;

    // fp8 staging geometry (one 16B chunk / thread covers 16 cols of a row)
    const int rf  = t >> 2;
    const int qf  = t & 3;
    const int wf8b = rf * 64 + (((2 * qf) ^ (rf & 6)) * 8);      // byte offset
    const size_t gf8 = (size_t)min(rBase + rf, N - 1) * 256 + qf * 16;

    f32x4 acc[4][4] = {};
    uint4 Ra0, Ra1, Rb0, Rb1, Rc0, Rc1;
    bf16x8 Bb0[8], Bb1[8];
    long long B8a[8], B8b[8];

    // prologue: x tiles 0,1,2 + B(0); tile0 -> At0
    LDX(Ra0, Ra1, 0);
    LDX(Rb0, Rb1, 1);
    LDX(Rc0, Rc1, 2);
    PBX(Bb0, 0);
    WRX(At0, Ra0, Ra1);
    FB;

    /*s0*/ WRX(At1, Rb0, Rb1); PBX(Bb1, 1);      MMX(At0, Bb0); LDX(Ra0, Ra1, 3); FB;
    /*s1*/ WRX(At0, Rc0, Rc1); PBX(Bb0, 2);      MMX(At1, Bb1); LD8(Rb0, s8i, 0); FB;
    /*s2*/ WRX(At1, Ra0, Ra1); PBX(Bb1, 3);      MMX(At0, Bb0); LD8(Rc0, s8i, 1); FB;
    /*s3*/ WR8(At0, Rb0);      PB8(B8a, W8I, 0); MMX(At1, Bb1); LD8(Ra0, s8i, 2); FB;
    /*s4*/ WR8(At1, Rc0);      PB8(B8b, W8I, 1); MM8(At0, B8a); LD8(Rb0, s8i, 3); FB;
    /*s5*/ WR8(At0, Ra0);      PB8(B8a, W8I, 2); MM8(At1, B8b); LD8(Rc0, s8o, 0); FB;
    /*s6*/ WR8(At1, Rb0);      PB8(B8b, W8I, 3); MM8(At0, B8a); LD8(Ra0, s8o, 1); FB;
    /*s7*/ WR8(At0, Rc0);      PB8(B8a, W8O, 0); MM8(At1, B8b); LD8(Rb0, s8o, 2); FB;
    /*s8*/ WR8(At1, Ra0);      PB8(B8b, W8O, 1); MM8(At0, B8a); LD8(Rc0, s8o, 3); FB;
    /*s9*/ WR8(At0, Rb0);      PB8(B8a, W8O, 2); MM8(At1, B8b); FB;
    /*s10*/WR8(At1, Rc0);      PB8(B8b, W8O, 3); MM8(At0, B8a); FB;
    /*s11*/                                      MM8(At1, B8b); FB;

    const int rb4 = lq * 4;
    const float resv = resPtr[0];

    if (!HEAD) {
        // ---- coalesced epilogue: stage res*tanh(acc+bias) in LDS halves ----
        unsigned short* C = lds;
        #pragma unroll
        for (int half = 0; half < 2; ++half) {
            if ((w >> 1) == half) {
                #pragma unroll
                for (int m = 0; m < 4; ++m) {
                    #pragma unroll
                    for (int i = 0; i < 4; ++i) {
                        int r6 = 16 * m + rb4 + i;
                        #pragma unroll
                        for (int n = 0; n < 4; ++n) {
                            int cH = (w & 1) * 64 + lr + 16 * n;
                            float v = acc[m][n][i] + bias[half * 128 + cH];
                            C[r6 * 128 + cH] = f2b(resv * ftanh(v));
                        }
                    }
                }
            }
            __syncthreads();
            #pragma unroll
            for (int ii = 0; ii < 4; ++ii) {
                int g   = ii * 256 + t;
                int r   = g >> 4;
                int cc  = g & 15;
                int row = rBase + r;
                if (row < N) {
                    bf16x8 sv = *(const bf16x8*)(&C[r * 128 + cc * 8]);
                    const unsigned short* ar = a0 + (size_t)row * D + half * 128 + cc * 8;
                    uint4 av = *(const uint4*)ar;
                    unsigned aw[4] = { av.x, av.y, av.z, av.w };
                    unsigned ow[4];
                    #pragma unroll
                    for (int p = 0; p < 4; ++p) {
                        float h0 = b2f((unsigned short)(aw[p] & 0xffff)) + b2f((unsigned short)sv[2 * p]);
                        float h1 = b2f((unsigned short)(aw[p] >> 16))    + b2f((unsigned short)sv[2 * p + 1]);
                        ow[p] = (unsigned)f2b(h0) | ((unsigned)f2b(h1) << 16);
                    }
                    *(uint4*)(outB + (size_t)row * D + half * 128 + cc * 8) =
                        make_uint4(ow[0], ow[1], ow[2], ow[3]);
                }
            }
            __syncthreads();
        }
    } else {
        // ---- HEAD: h2 -> swizzled LDS tile, then out = h2 @ WfMu + mub ----
        #pragma unroll
        for (int m = 0; m < 4; ++m) {
            #pragma unroll
            for (int i = 0; i < 4; ++i) {
                int row = rBase + 16 * m + rb4 + i;
                if (row < N) {
                    size_t base = (size_t)row * D + w * 64 + lr;
                    int r6 = 16 * m + rb4 + i;
                    #pragma unroll
                    for (int n = 0; n < 4; ++n) {
                        int   c = w * 64 + lr + 16 * n;
                        float v = acc[m][n][i] + bias[c];
                        float h = b2f(a0[base + 16 * n]) + resv * ftanh(v);
                        lds[r6 * 256 + (c ^ ((r6 & 7) << 3))] = f2b(h);
                    }
                }
            }
        }
        __syncthreads();
        #pragma unroll
        for (int m = 0; m < 4; ++m) {
            #pragma unroll
            for (int n = 0; n < 4; ++n)
                acc[m][n] = (f32x4){0.f, 0.f, 0.f, 0.f};
        }

        #pragma unroll
        for (int s2 = 0; s2 < 4; ++s2) {
            #pragma unroll
            for (int kk = 0; kk < 2; ++kk) {
                const int kg = s2 * 2 + kk;
                bf16x8 a_[4], b_[4];
                #pragma unroll
                for (int m = 0; m < 4; ++m) {
                    int rm = 16 * m + lr;
                    int ch = (s2 * 8 + kk * 4 + lq) ^ (rm & 7);
                    a_[m] = *(const bf16x8*)(&lds[rm * 256 + ch * 8]);
                }
                #pragma unroll
                for (int n = 0; n < 4; ++n)
                    b_[n] = *(const bf16x8*)(WfMu + (((kg * 16 + (w * 4 + n)) * 64 + l) * 8));
                #pragma unroll
                for (int m = 0; m < 4; ++m) {
                    #pragma unroll
                    for (int n = 0; n < 4; ++n)
                        acc[m][n] = __builtin_amdgcn_mfma_f32_16x16x32_bf16(a_[m], b_[n], acc[m][n], 0, 0, 0);
                }
            }
        }

        __syncthreads();
        float* Cf = (float*)lds;
        #pragma unroll
        for (int half = 0; half < 2; ++half) {
            if ((w >> 1) == half) {
                #pragma unroll
                for (int m = 0; m < 4; ++m) {
                    #pragma unroll
                    for (int i = 0; i < 4; ++i) {
                        int r6 = 16 * m + rb4 + i;
                        #pragma unroll
                        for (int n = 0; n < 4; ++n) {
                            int cH = (w & 1) * 64 + lr + 16 * n;
                            Cf[r6 * 128 + cH] = acc[m][n][i] + mub[half * 128 + cH];
                        }
                    }
                }
            }
            __syncthreads();
            #pragma unroll
            for (int ii = 0; ii < 8; ++ii) {
                int g   = ii * 256 + t;
                int r   = g >> 5;
                int cc  = g & 31;
                int row = rBase + r;
                if (row < N) {
                    *(float4*)(outF + (size_t)row * D + half * 128 + cc * 4) =
                        *(const float4*)(&Cf[r * 128 + cc * 4]);
                }
            }
            __syncthreads();
        }
    }
}

// ---------------------------------------------------------------------------

extern "C" void kernel_launch(void* const* d_in, const int* in_sizes, int n_in,
                              void* d_out, int out_size, void* d_ws, size_t ws_size,
                              hipStream_t stream)
{
    const float* emb  = (const float*)d_in[0];
    const int*   ei   = (const int*)  d_in[1];
    const int*   et   = (const int*)  d_in[2];
    const float* rel1 = (const float*)d_in[3];
    const float* Wi1  = (const float*)d_in[4];
    const float* Wo1  = (const float*)d_in[5];
    const float* Wl1  = (const float*)d_in[6];
    const float* b1   = (const float*)d_in[7];
    const float* rel2 = (const float*)d_in[8];
    const float* Wi2  = (const float*)d_in[9];
    const float* Wo2  = (const float*)d_in[10];
    const float* Wl2  = (const float*)d_in[11];
    const float* b2   = (const float*)d_in[12];
    const float* res  = (const float*)d_in[13];
    const float* muw  = (const float*)d_in[14];
    const float* mub  = (const float*)d_in[15];

    const int D = in_sizes[7];          // 256
    const int N = in_sizes[0] / D;      // 50000
    const int E = in_sizes[2];          // 320000
    const int R = in_sizes[3] / D;      // 400
    const int halfE = E / 2;
    const int* srcA = ei;
    const int* dstA = ei + E;
    const size_t DD = (size_t)D * D;

    char* ws = (char*)d_ws;
    size_t off = 0;
    auto alloc = [&](size_t bytes) -> char* {
        char* p = ws + off; off += (bytes + 255) & ~(size_t)255; return p;
    };
    const int nb1 = (N + 255) / 256;

    float*          norm   = (float*)          alloc((size_t)N * 4);
    int*            cnt    = (int*)            alloc((size_t)N * 4);
    int*            rowptr = (int*)            alloc((size_t)(N + 1) * 4);
    int*            cursor = (int*)            alloc((size_t)N * 4);
    int*            part   = (int*)            alloc((size_t)N * 4);
    int*            bsum   = (int*)            alloc(1024);
    unsigned*       erec   = (unsigned*)       alloc((size_t)E * 4);
    unsigned short* xb     = (unsigned short*) alloc((size_t)N * D * 2);
    unsigned short* h1b    = (unsigned short*) alloc((size_t)N * D * 2);
    unsigned char*  sIn8   = (unsigned char*)  alloc((size_t)N * D);
    unsigned char*  sOut8  = (unsigned char*)  alloc((size_t)N * D);
    unsigned short* r1b    = (unsigned short*) alloc((size_t)R * D * 2);
    unsigned short* r2b    = (unsigned short*) alloc((size_t)R * D * 2);
    unsigned short* fAll   = (unsigned short*) alloc(3 * DD * 2);   // Wl1, Wl2, mu
    unsigned char*  f8All  = (unsigned char*)  alloc(4 * DD);       // Wi1,Wo1,Wi2,Wo2
    if (off > ws_size) return;

    unsigned short* fWl1 = fAll;
    unsigned short* fWl2 = fAll + DD;
    unsigned short* fMu  = fAll + 2 * DD;
    unsigned char*  f8Wi1 = f8All;
    unsigned char*  f8Wo1 = f8All + DD;
    unsigned char*  f8Wi2 = f8All + 2 * DD;
    unsigned char*  f8Wo2 = f8All + 3 * DD;

    // --- CSR + norm ---
    hipMemsetAsync(cnt, 0, (size_t)N * 4, stream);
    k_hist   <<<(E + 255) / 256, 256, 0, stream>>>(dstA, cnt, E);
    k_norm   <<<nb1, 256, 0, stream>>>(cnt, norm, N);
    k_scan1  <<<nb1, 256, 0, stream>>>(cnt, part, bsum, N);
    k_scan2  <<<1,   256, 0, stream>>>(bsum, nb1);
    k_scan3  <<<nb1, 256, 0, stream>>>(part, bsum, rowptr, cursor, N, E);
    k_scatter<<<(E + 255) / 256, 256, 0, stream>>>(srcA, dstA, et, cursor, erec, E, halfE);

    // --- dtype prep ---
    long nd4 = (long)N * D / 4, rd4 = (long)R * D / 4;
    long tot4 = nd4 + 2 * rd4;
    k_cvt3<<<(int)((tot4 + 255) / 256), 256, 0, stream>>>(
        emb, xb, nd4, rel1, r1b, rd4, rel2, r2b, rd4);
    k_wfrag3<<<(int)(3 * DD / 256), 256, 0, stream>>>(Wl1, Wl2, muw, fAll);
    k_wfrag8<<<(int)(4 * DD / 1024), 256, 0, stream>>>(Wi1, Wo1, Wi2, Wo2, f8All);

    const int AB = (N + 3) / 4;
    const int NB = (N + 63) / 64;

    // --- layer 1 ---
    k_agg<<<AB, 256, 0, stream>>>(xb, r1b, rowptr, erec, norm, sIn8, sOut8, N, D);
    k_gemm<false><<<NB, 256, 0, stream>>>(xb, sIn8, sOut8, fWl1, f8Wi1, f8Wo1, b1, res,
                                          nullptr, nullptr, nullptr, h1b, N, D);

    // --- layer 2 + head ---
    k_agg<<<AB, 256, 0, stream>>>(h1b, r2b, rowptr, erec, norm, sIn8, sOut8, N, D);
    k_gemm<true><<<NB, 256, 0, stream>>>(h1b, sIn8, sOut8, fWl2, f8Wi2, f8Wo2, b2, res,
                                         fMu, mub, (float*)d_out, nullptr, N, D);
}

// Round 14
// 206.166 us; speedup vs baseline: 1.2127x; 1.1275x over previous
//
#include <hip/hip_runtime.h>
#include <hip/hip_bf16.h>
#include <cstdint>
#include <cstddef>

// ---------------------------------------------------------------------------
// MGCN (2-layer relational GCN + linear head).
//
//   s_in[v]  = norm[v] * sum_{first-half edges,  dst=v} x[src]*rel[ty]
//   s_out[v] = norm[v] * sum_{second-half edges, dst=v} x[src]*rel[ty]
//   h        = x + res * tanh( x@W_loop + s_in@W_in + s_out@W_out + b )
//   out      = h2 @ mu_w + mu_b     (fused into layer-2 kernel)
//
// R13 + fp8 GATHER: k_agg reads fp8 copies of x/h1 and rel (half the cache
// gather volume), decoding with HW v_cvt_pk_f32_fp8.  s_in/s_out stay fp8;
// GEMM unchanged from R13 (bf16 x-part + fp8 s-part).
// ---------------------------------------------------------------------------

typedef short bf16x8 __attribute__((ext_vector_type(8)));
typedef float f32x4  __attribute__((ext_vector_type(4)));
typedef float f32x2  __attribute__((ext_vector_type(2)));

__device__ __forceinline__ float b2f(unsigned short u) {
    union { unsigned u32; float f; } c; c.u32 = ((unsigned)u) << 16; return c.f;
}
__device__ __forceinline__ unsigned short f2b(float f) {
    union { float f; unsigned u; } c; c.f = f;
    unsigned r = c.u + 0x7FFFu + ((c.u >> 16) & 1u);   // RNE
    return (unsigned short)(r >> 16);
}
__device__ __forceinline__ float ftanh(float x) {
    float e = __expf(2.0f * x);
    return 1.0f - __fdividef(2.0f, e + 1.0f);
}

// f32 -> fp8 e4m3fn (OCP), RNE, saturating (software fallback).
__device__ __forceinline__ unsigned char f2e4m3(float f) {
    unsigned u = __float_as_uint(f);
    unsigned s = (u >> 24) & 0x80u;
    unsigned a = u & 0x7fffffffu;
    if (a >= 0x43e00000u) return (unsigned char)(s | 0x7eu);      // >=448 -> max
    if (a < 0x3c800000u) {                                        // < 2^-6: subnormal
        float m = __uint_as_float(a) * 512.0f;
        int q = (int)rintf(m);
        if (q == 8) return (unsigned char)(s | 0x08u);
        return (unsigned char)(s | (unsigned)q);
    }
    unsigned m = a & 0x7fffffu;
    unsigned e = a >> 23;
    unsigned r = m + 0x7ffffu + ((m >> 20) & 1u);
    if (r >= 0x800000u) { e += 1; r -= 0x800000u; }
    if (e > 127u + 8u) return (unsigned char)(s | 0x7eu);
    return (unsigned char)(s | ((e - 127u + 7u) << 3) | (r >> 20));
}

// pack 4 floats -> 4 fp8 bytes (HW converter when available)
__device__ __forceinline__ unsigned pk8_4(float a, float b, float c, float d) {
#if __has_builtin(__builtin_amdgcn_cvt_pk_fp8_f32)
    int v = 0;
    v = __builtin_amdgcn_cvt_pk_fp8_f32(a, b, v, false);
    v = __builtin_amdgcn_cvt_pk_fp8_f32(c, d, v, true);
    return (unsigned)v;
#else
    return (unsigned)f2e4m3(a) | ((unsigned)f2e4m3(b) << 8)
         | ((unsigned)f2e4m3(c) << 16) | ((unsigned)f2e4m3(d) << 24);
#endif
}

// unpack 4 fp8 bytes -> 4 floats (HW converter when available)
__device__ __forceinline__ void dec4(unsigned u, float* f) {
#if __has_builtin(__builtin_amdgcn_cvt_pk_f32_fp8)
    f32x2 lo = __builtin_amdgcn_cvt_pk_f32_fp8((int)u, false);
    f32x2 hi = __builtin_amdgcn_cvt_pk_f32_fp8((int)u, true);
    f[0] = lo[0]; f[1] = lo[1]; f[2] = hi[0]; f[3] = hi[1];
#else
    #pragma unroll
    for (int i = 0; i < 4; ++i) {
        unsigned b = (u >> (8 * i)) & 0xffu;
        unsigned em = b & 0x7fu;
        float mag;
        if (em >= 8u) mag = __uint_as_float((((em >> 3) + 120u) << 23) | ((em & 7u) << 20));
        else          mag = (float)em * 0.001953125f;     // * 2^-9
        f[i] = (b & 0x80u) ? -mag : mag;
    }
#endif
}

// ---- CSR construction ------------------------------------------------------

__global__ void k_hist(const int* __restrict__ dst, int* __restrict__ cnt, int E) {
    int i = blockIdx.x * blockDim.x + threadIdx.x;
    if (i < E) atomicAdd(&cnt[dst[i]], 1);
}

__global__ void k_norm(const int* __restrict__ cnt, float* __restrict__ norm, int N) {
    int i = blockIdx.x * blockDim.x + threadIdx.x;
    if (i < N) norm[i] = 1.0f / fmaxf((float)cnt[i], 1.0f);
}

__global__ void k_scan1(const int* __restrict__ cnt, int* __restrict__ part,
                        int* __restrict__ bsum, int N) {
    __shared__ int s[256];
    int i = blockIdx.x * 256 + threadIdx.x;
    int v = (i < N) ? cnt[i] : 0;
    s[threadIdx.x] = v; __syncthreads();
    #pragma unroll
    for (int o = 1; o < 256; o <<= 1) {
        int t = (threadIdx.x >= o) ? s[threadIdx.x - o] : 0;
        __syncthreads();
        s[threadIdx.x] += t;
        __syncthreads();
    }
    if (i < N) part[i] = s[threadIdx.x] - v;
    if (threadIdx.x == 255) bsum[blockIdx.x] = s[255];
}

__global__ void k_scan2(int* __restrict__ bsum, int nb) {
    __shared__ int s[256];
    int v = (threadIdx.x < nb) ? bsum[threadIdx.x] : 0;
    s[threadIdx.x] = v; __syncthreads();
    #pragma unroll
    for (int o = 1; o < 256; o <<= 1) {
        int t = (threadIdx.x >= o) ? s[threadIdx.x - o] : 0;
        __syncthreads();
        s[threadIdx.x] += t;
        __syncthreads();
    }
    if (threadIdx.x < nb) bsum[threadIdx.x] = s[threadIdx.x] - v;
}

__global__ void k_scan3(const int* __restrict__ part, const int* __restrict__ bsum,
                        int* __restrict__ rowptr, int* __restrict__ cursor, int N, int E) {
    int i = blockIdx.x * 256 + threadIdx.x;
    if (i < N) {
        int r = part[i] + bsum[blockIdx.x];
        rowptr[i] = r; cursor[i] = r;
    }
    if (i == 0) rowptr[N] = E;
}

__global__ void k_scatter(const int* __restrict__ src, const int* __restrict__ dst,
                          const int* __restrict__ et, int* __restrict__ cursor,
                          unsigned* __restrict__ erec, int E, int halfE) {
    int e = blockIdx.x * blockDim.x + threadIdx.x;
    if (e < E) {
        int d = dst[e];
        int pos = atomicAdd(&cursor[d], 1);
        unsigned rec = (unsigned)src[e] | ((unsigned)et[e] << 16)
                     | ((e >= halfE) ? 0x80000000u : 0u);
        erec[pos] = rec;
    }
}

// ---- dtype prep: f32 -> bf16 + fp8 ----------------------------------------

__global__ void k_cvtx3(const float* __restrict__ s0, unsigned short* __restrict__ d0,
                        unsigned char* __restrict__ e0, long n0,
                        const float* __restrict__ s1, unsigned short* __restrict__ d1,
                        unsigned char* __restrict__ e1, long n1,
                        const float* __restrict__ s2, unsigned short* __restrict__ d2,
                        unsigned char* __restrict__ e2, long n2) {
    long i = (long)blockIdx.x * blockDim.x + threadIdx.x;
    const float* s; unsigned short* d; unsigned char* e; long j = i;
    if (j < n0) { s = s0; d = d0; e = e0; }
    else {
        j -= n0;
        if (j < n1) { s = s1; d = d1; e = e1; }
        else { j -= n1; if (j >= n2) return; s = s2; d = d2; e = e2; }
    }
    float4 v = ((const float4*)s)[j];
    ushort4 o;
    o.x = f2b(v.x); o.y = f2b(v.y); o.z = f2b(v.z); o.w = f2b(v.w);
    ((ushort4*)d)[j] = o;
    ((unsigned*)e)[j] = pk8_4(v.x, v.y, v.z, v.w);
}

// bf16 fragment tables: W_loop1, W_loop2, mu_w
__global__ void k_wfrag3(const float* __restrict__ w0, const float* __restrict__ w1,
                         const float* __restrict__ w2, unsigned short* __restrict__ out) {
    int o = blockIdx.x * 256 + threadIdx.x;      // grid = 3*65536/256
    int mi = o >> 16;
    int r  = o & 65535;
    const float* W = (mi == 0) ? w0 : (mi == 1) ? w1 : w2;
    int j  = r & 7;
    int l  = (r >> 3) & 63;
    int nn = (r >> 9) & 15;
    int kg = r >> 13;
    int k = kg * 32 + (l >> 4) * 8 + j;
    int n = nn * 16 + (l & 15);
    out[o] = f2b(W[k * 256 + n]);
}

// fp8 fragment tables: W_in1, W_out1, W_in2, W_out2 (8-byte frags)
__global__ void k_wfrag8(const float* __restrict__ w0, const float* __restrict__ w1,
                         const float* __restrict__ w2, const float* __restrict__ w3,
                         unsigned char* __restrict__ out) {
    int o = (blockIdx.x * 256 + threadIdx.x) * 4;    // grid = 4*65536/1024
    int mi = o >> 16;
    int r  = o & 65535;
    const float* W = (mi == 0) ? w0 : (mi == 1) ? w1 : (mi == 2) ? w2 : w3;
    int j0 = r & 7;
    int l  = (r >> 3) & 63;
    int nn = (r >> 9) & 15;
    int kg = r >> 13;
    int n  = nn * 16 + (l & 15);
    int kb = kg * 32 + (l >> 4) * 8 + j0;
    *(unsigned*)(out + o) = pk8_4(W[(kb + 0) * 256 + n], W[(kb + 1) * 256 + n],
                                  W[(kb + 2) * 256 + n], W[(kb + 3) * 256 + n]);
}

// ---- CSR gather aggregation: fp8 inputs, fp8 outputs, 4-edge pipeline -----

__global__ __launch_bounds__(256)
void k_agg(const unsigned char* __restrict__ x8, const unsigned char* __restrict__ rel8,
           const int* __restrict__ rowptr, const unsigned* __restrict__ erec,
           const float* __restrict__ norm,
           unsigned char* __restrict__ sIn8, unsigned char* __restrict__ sOut8,
           int N, int D)
{
    const int w = threadIdx.x >> 6, l = threadIdx.x & 63;
    const int v = blockIdx.x * 4 + w;
    if (v >= N) return;
    const int rs = rowptr[v], re = rowptr[v + 1];
    const float nm = norm[v];

    float ai0 = 0, ai1 = 0, ai2 = 0, ai3 = 0;
    float ao0 = 0, ao1 = 0, ao2 = 0, ao3 = 0;

    unsigned c0 = (rs     < re) ? erec[rs]     : 0u;
    unsigned c1 = (rs + 1 < re) ? erec[rs + 1] : 0u;
    unsigned c2 = (rs + 2 < re) ? erec[rs + 2] : 0u;
    unsigned c3 = (rs + 3 < re) ? erec[rs + 3] : 0u;
    int i = rs;
    while (i + 4 <= re) {
        unsigned m0 = (i + 4 < re) ? erec[i + 4] : 0u;
        unsigned m1 = (i + 5 < re) ? erec[i + 5] : 0u;
        unsigned m2 = (i + 6 < re) ? erec[i + 6] : 0u;
        unsigned m3 = (i + 7 < re) ? erec[i + 7] : 0u;
        unsigned xu0 = *(const unsigned*)(x8   + (size_t)(c0 & 0xffff) * 256 + l * 4);
        unsigned ru0 = *(const unsigned*)(rel8 + (size_t)((c0 >> 16) & 0x7fff) * 256 + l * 4);
        unsigned xu1 = *(const unsigned*)(x8   + (size_t)(c1 & 0xffff) * 256 + l * 4);
        unsigned ru1 = *(const unsigned*)(rel8 + (size_t)((c1 >> 16) & 0x7fff) * 256 + l * 4);
        unsigned xu2 = *(const unsigned*)(x8   + (size_t)(c2 & 0xffff) * 256 + l * 4);
        unsigned ru2 = *(const unsigned*)(rel8 + (size_t)((c2 >> 16) & 0x7fff) * 256 + l * 4);
        unsigned xu3 = *(const unsigned*)(x8   + (size_t)(c3 & 0xffff) * 256 + l * 4);
        unsigned ru3 = *(const unsigned*)(rel8 + (size_t)((c3 >> 16) & 0x7fff) * 256 + l * 4);
        float xf[4], rf[4];
        dec4(xu0, xf); dec4(ru0, rf);
        if (c0 >> 31) { ao0 += xf[0]*rf[0]; ao1 += xf[1]*rf[1]; ao2 += xf[2]*rf[2]; ao3 += xf[3]*rf[3]; }
        else          { ai0 += xf[0]*rf[0]; ai1 += xf[1]*rf[1]; ai2 += xf[2]*rf[2]; ai3 += xf[3]*rf[3]; }
        dec4(xu1, xf); dec4(ru1, rf);
        if (c1 >> 31) { ao0 += xf[0]*rf[0]; ao1 += xf[1]*rf[1]; ao2 += xf[2]*rf[2]; ao3 += xf[3]*rf[3]; }
        else          { ai0 += xf[0]*rf[0]; ai1 += xf[1]*rf[1]; ai2 += xf[2]*rf[2]; ai3 += xf[3]*rf[3]; }
        dec4(xu2, xf); dec4(ru2, rf);
        if (c2 >> 31) { ao0 += xf[0]*rf[0]; ao1 += xf[1]*rf[1]; ao2 += xf[2]*rf[2]; ao3 += xf[3]*rf[3]; }
        else          { ai0 += xf[0]*rf[0]; ai1 += xf[1]*rf[1]; ai2 += xf[2]*rf[2]; ai3 += xf[3]*rf[3]; }
        dec4(xu3, xf); dec4(ru3, rf);
        if (c3 >> 31) { ao0 += xf[0]*rf[0]; ao1 += xf[1]*rf[1]; ao2 += xf[2]*rf[2]; ao3 += xf[3]*rf[3]; }
        else          { ai0 += xf[0]*rf[0]; ai1 += xf[1]*rf[1]; ai2 += xf[2]*rf[2]; ai3 += xf[3]*rf[3]; }
        c0 = m0; c1 = m1; c2 = m2; c3 = m3; i += 4;
    }
    #pragma unroll
    for (int j = 0; j < 3; ++j) {
        if (i + j < re) {
            unsigned cur = (j == 0) ? c0 : (j == 1) ? c1 : c2;
            unsigned xu = *(const unsigned*)(x8   + (size_t)(cur & 0xffff) * 256 + l * 4);
            unsigned ru = *(const unsigned*)(rel8 + (size_t)((cur >> 16) & 0x7fff) * 256 + l * 4);
            float xf[4], rf[4];
            dec4(xu, xf); dec4(ru, rf);
            if (cur >> 31) { ao0 += xf[0]*rf[0]; ao1 += xf[1]*rf[1]; ao2 += xf[2]*rf[2]; ao3 += xf[3]*rf[3]; }
            else           { ai0 += xf[0]*rf[0]; ai1 += xf[1]*rf[1]; ai2 += xf[2]*rf[2]; ai3 += xf[3]*rf[3]; }
        }
    }

    *(unsigned*)(sIn8  + (size_t)v * 256 + l * 4) = pk8_4(ai0 * nm, ai1 * nm, ai2 * nm, ai3 * nm);
    *(unsigned*)(sOut8 + (size_t)v * 256 + l * 4) = pk8_4(ao0 * nm, ao1 * nm, ao2 * nm, ao3 * nm);
}

// ---- hybrid bf16/fp8 GEMM (R13, verified) ----------------------------------

#define FB  do { asm volatile("s_waitcnt lgkmcnt(0)" ::: "memory");             \
                 __builtin_amdgcn_sched_barrier(0);                             \
                 __builtin_amdgcn_s_barrier();                                  \
                 __builtin_amdgcn_sched_barrier(0); } while (0)

#define WRX(AtN, R0, R1) do { *(uint4*)(&(AtN)[wo0]) = R0;                      \
                              *(uint4*)(&(AtN)[wo1]) = R1; } while (0)
#define WR8(AtN, R0)     do { *(uint4*)(((char*)(AtN)) + wf8b) = R0; } while (0)
#define LDX(R0, R1, CB)  do { R0 = *(const uint4*)(a0 + g0 + (CB)*64);          \
                              R1 = *(const uint4*)(a0 + g1 + (CB)*64); } while (0)
#define LD8(R0, SRC, CB) do { R0 = *(const uint4*)((SRC) + gf8 + (CB)*64); } while (0)

#define PBX(Bn, CB)                                                             \
  do { _Pragma("unroll")                                                        \
       for (int kk_ = 0; kk_ < 2; ++kk_) {                                      \
         _Pragma("unroll")                                                      \
         for (int n_ = 0; n_ < 4; ++n_)                                         \
           Bn[kk_*4+n_] = *(const bf16x8*)(WfL +                                \
               ((((CB)*2+kk_)*16 + (w*4+n_))*64 + l)*8);                        \
       } } while (0)

#define PB8(Bn, TBL, CB)                                                        \
  do { _Pragma("unroll")                                                        \
       for (int kk_ = 0; kk_ < 2; ++kk_) {                                      \
         _Pragma("unroll")                                                      \
         for (int n_ = 0; n_ < 4; ++n_)                                         \
           Bn[kk_*4+n_] = *(const long long*)((TBL) +                           \
               ((((CB)*2+kk_)*16 + (w*4+n_))*64 + l)*8);                        \
       } } while (0)

#define MMX(AtC, Bc)                                                            \
  do { _Pragma("unroll")                                                        \
       for (int kk_ = 0; kk_ < 2; ++kk_) {                                      \
         bf16x8 a_[4];                                                          \
         _Pragma("unroll")                                                      \
         for (int m_ = 0; m_ < 4; ++m_) {                                       \
           int rm_ = 16*m_ + lr; int ch_ = (kk_*4+lq) ^ (rm_ & 7);              \
           a_[m_] = *(const bf16x8*)(&(AtC)[rm_*64 + ch_*8]);                   \
         }                                                                      \
         _Pragma("unroll")                                                      \
         for (int m_ = 0; m_ < 4; ++m_) {                                       \
           _Pragma("unroll")                                                    \
           for (int n_ = 0; n_ < 4; ++n_)                                       \
             acc[m_][n_] = __builtin_amdgcn_mfma_f32_16x16x32_bf16(             \
                 a_[m_], Bc[kk_*4+n_], acc[m_][n_], 0, 0, 0);                   \
         } } } while (0)

#define MM8(AtC, Bc)                                                            \
  do { const char* A8_ = (const char*)(AtC);                                    \
       _Pragma("unroll")                                                        \
       for (int kk_ = 0; kk_ < 2; ++kk_) {                                      \
         long long a_[4];                                                       \
         _Pragma("unroll")                                                      \
         for (int m_ = 0; m_ < 4; ++m_) {                                       \
           int rm_ = 16*m_ + lr; int ch_ = (kk_*4+lq) ^ (rm_ & 6);              \
           a_[m_] = *(const long long*)(A8_ + rm_*64 + ch_*8);                  \
         }                                                                      \
         _Pragma("unroll")                                                      \
         for (int m_ = 0; m_ < 4; ++m_) {                                       \
           _Pragma("unroll")                                                    \
           for (int n_ = 0; n_ < 4; ++n_)                                       \
             acc[m_][n_] = __builtin_amdgcn_mfma_f32_16x16x32_fp8_fp8(          \
                 a_[m_], Bc[kk_*4+n_], acc[m_][n_], 0, 0, 0);                   \
         } } } while (0)

template <bool HEAD>
__global__ __launch_bounds__(256, 2)
void k_gemm(const unsigned short* __restrict__ a0,     // [N,256] bf16 x / h1
            const unsigned char*  __restrict__ s8i,    // [N,256] fp8 sIn
            const unsigned char*  __restrict__ s8o,    // [N,256] fp8 sOut
            const unsigned short* __restrict__ WfL,    // bf16 frag table (W_loop)
            const unsigned char*  __restrict__ W8I,    // fp8 frag table (W_in)
            const unsigned char*  __restrict__ W8O,    // fp8 frag table (W_out)
            const float* __restrict__ bias,
            const float* __restrict__ resPtr,
            const unsigned short* __restrict__ WfMu,   // bf16 frag table (HEAD)
            const float* __restrict__ mub,             // (HEAD)
            float* __restrict__ outF,                  // (HEAD)
            unsigned short* __restrict__ outB,         // (!HEAD)
            unsigned char* __restrict__ outB8,         // (!HEAD) fp8 h copy
            int N, int D)
{
    __shared__ unsigned short lds[HEAD ? 16384 : 8192];
    unsigned short* At0 = lds;
    unsigned short* At1 = lds + 4096;

    const int t = threadIdx.x;
    const int rBase = blockIdx.x * 64;

    const int w  = t >> 6;
    const int l  = t & 63;
    const int lr = l & 15;
    const int lq = l >> 4;

    const int rS0 = t >> 3;
    const int rS1 = rS0 + 32;
    const int cS  = t & 7;
    const int wo0 = rS0 * 64 + ((cS ^ (rS0 & 7)) * 8);
    const int wo1 = rS1 * 64 + ((cS ^ (rS1 & 7)) * 8);
    const size_t g0 = (size_t)min(rBase + rS0, N - 1) * 256 + cS * 8;
    const size_t g1 = (size_t)min(rBase + rS1, N - 1) * 256 + cS * 8;

    const int rf  = t >> 2;
    const int qf  = t & 3;
    const int wf8b = rf * 64 + (((2 * qf) ^ (rf & 6)) * 8);      // byte offset
    const size_t gf8 = (size_t)min(rBase + rf, N - 1) * 256 + qf * 16;

    f32x4 acc[4][4] = {};
    uint4 Ra0, Ra1, Rb0, Rb1, Rc0, Rc1;
    bf16x8 Bb0[8], Bb1[8];
    long long B8a[8], B8b[8];

    LDX(Ra0, Ra1, 0);
    LDX(Rb0, Rb1, 1);
    LDX(Rc0, Rc1, 2);
    PBX(Bb0, 0);
    WRX(At0, Ra0, Ra1);
    FB;

    /*s0*/ WRX(At1, Rb0, Rb1); PBX(Bb1, 1);      MMX(At0, Bb0); LDX(Ra0, Ra1, 3); FB;
    /*s1*/ WRX(At0, Rc0, Rc1); PBX(Bb0, 2);      MMX(At1, Bb1); LD8(Rb0, s8i, 0); FB;
    /*s2*/ WRX(At1, Ra0, Ra1); PBX(Bb1, 3);      MMX(At0, Bb0); LD8(Rc0, s8i, 1); FB;
    /*s3*/ WR8(At0, Rb0);      PB8(B8a, W8I, 0); MMX(At1, Bb1); LD8(Ra0, s8i, 2); FB;
    /*s4*/ WR8(At1, Rc0);      PB8(B8b, W8I, 1); MM8(At0, B8a); LD8(Rb0, s8i, 3); FB;
    /*s5*/ WR8(At0, Ra0);      PB8(B8a, W8I, 2); MM8(At1, B8b); LD8(Rc0, s8o, 0); FB;
    /*s6*/ WR8(At1, Rb0);      PB8(B8b, W8I, 3); MM8(At0, B8a); LD8(Ra0, s8o, 1); FB;
    /*s7*/ WR8(At0, Rc0);      PB8(B8a, W8O, 0); MM8(At1, B8b); LD8(Rb0, s8o, 2); FB;
    /*s8*/ WR8(At1, Ra0);      PB8(B8b, W8O, 1); MM8(At0, B8a); LD8(Rc0, s8o, 3); FB;
    /*s9*/ WR8(At0, Rb0);      PB8(B8a, W8O, 2); MM8(At1, B8b); FB;
    /*s10*/WR8(At1, Rc0);      PB8(B8b, W8O, 3); MM8(At0, B8a); FB;
    /*s11*/                                      MM8(At1, B8b); FB;

    const int rb4 = lq * 4;
    const float resv = resPtr[0];

    if (!HEAD) {
        // ---- coalesced epilogue: stage res*tanh(acc+bias) in LDS halves ----
        unsigned short* C = lds;
        #pragma unroll
        for (int half = 0; half < 2; ++half) {
            if ((w >> 1) == half) {
                #pragma unroll
                for (int m = 0; m < 4; ++m) {
                    #pragma unroll
                    for (int i = 0; i < 4; ++i) {
                        int r6 = 16 * m + rb4 + i;
                        #pragma unroll
                        for (int n = 0; n < 4; ++n) {
                            int cH = (w & 1) * 64 + lr + 16 * n;
                            float v = acc[m][n][i] + bias[half * 128 + cH];
                            C[r6 * 128 + cH] = f2b(resv * ftanh(v));
                        }
                    }
                }
            }
            __syncthreads();
            #pragma unroll
            for (int ii = 0; ii < 4; ++ii) {
                int g   = ii * 256 + t;
                int r   = g >> 4;
                int cc  = g & 15;
                int row = rBase + r;
                if (row < N) {
                    bf16x8 sv = *(const bf16x8*)(&C[r * 128 + cc * 8]);
                    const unsigned short* ar = a0 + (size_t)row * D + half * 128 + cc * 8;
                    uint4 av = *(const uint4*)ar;
                    unsigned aw[4] = { av.x, av.y, av.z, av.w };
                    unsigned ow[4];
                    float hv[8];
                    #pragma unroll
                    for (int p = 0; p < 4; ++p) {
                        float h0 = b2f((unsigned short)(aw[p] & 0xffff)) + b2f((unsigned short)sv[2 * p]);
                        float h1 = b2f((unsigned short)(aw[p] >> 16))    + b2f((unsigned short)sv[2 * p + 1]);
                        hv[2 * p] = h0; hv[2 * p + 1] = h1;
                        ow[p] = (unsigned)f2b(h0) | ((unsigned)f2b(h1) << 16);
                    }
                    *(uint4*)(outB + (size_t)row * D + half * 128 + cc * 8) =
                        make_uint4(ow[0], ow[1], ow[2], ow[3]);
                    uint2 q;
                    q.x = pk8_4(hv[0], hv[1], hv[2], hv[3]);
                    q.y = pk8_4(hv[4], hv[5], hv[6], hv[7]);
                    *(uint2*)(outB8 + (size_t)row * 256 + half * 128 + cc * 8) = q;
                }
            }
            __syncthreads();
        }
    } else {
        // ---- HEAD: h2 -> swizzled LDS tile, then out = h2 @ WfMu + mub ----
        #pragma unroll
        for (int m = 0; m < 4; ++m) {
            #pragma unroll
            for (int i = 0; i < 4; ++i) {
                int row = rBase + 16 * m + rb4 + i;
                if (row < N) {
                    size_t base = (size_t)row * D + w * 64 + lr;
                    int r6 = 16 * m + rb4 + i;
                    #pragma unroll
                    for (int n = 0; n < 4; ++n) {
                        int   c = w * 64 + lr + 16 * n;
                        float v = acc[m][n][i] + bias[c];
                        float h = b2f(a0[base + 16 * n]) + resv * ftanh(v);
                        lds[r6 * 256 + (c ^ ((r6 & 7) << 3))] = f2b(h);
                    }
                }
            }
        }
        __syncthreads();
        #pragma unroll
        for (int m = 0; m < 4; ++m) {
            #pragma unroll
            for (int n = 0; n < 4; ++n)
                acc[m][n] = (f32x4){0.f, 0.f, 0.f, 0.f};
        }

        #pragma unroll
        for (int s2 = 0; s2 < 4; ++s2) {
            #pragma unroll
            for (int kk = 0; kk < 2; ++kk) {
                const int kg = s2 * 2 + kk;
                bf16x8 a_[4], b_[4];
                #pragma unroll
                for (int m = 0; m < 4; ++m) {
                    int rm = 16 * m + lr;
                    int ch = (s2 * 8 + kk * 4 + lq) ^ (rm & 7);
                    a_[m] = *(const bf16x8*)(&lds[rm * 256 + ch * 8]);
                }
                #pragma unroll
                for (int n = 0; n < 4; ++n)
                    b_[n] = *(const bf16x8*)(WfMu + (((kg * 16 + (w * 4 + n)) * 64 + l) * 8));
                #pragma unroll
                for (int m = 0; m < 4; ++m) {
                    #pragma unroll
                    for (int n = 0; n < 4; ++n)
                        acc[m][n] = __builtin_amdgcn_mfma_f32_16x16x32_bf16(a_[m], b_[n], acc[m][n], 0, 0, 0);
                }
            }
        }

        __syncthreads();
        float* Cf = (float*)lds;
        #pragma unroll
        for (int half = 0; half < 2; ++half) {
            if ((w >> 1) == half) {
                #pragma unroll
                for (int m = 0; m < 4; ++m) {
                    #pragma unroll
                    for (int i = 0; i < 4; ++i) {
                        int r6 = 16 * m + rb4 + i;
                        #pragma unroll
                        for (int n = 0; n < 4; ++n) {
                            int cH = (w & 1) * 64 + lr + 16 * n;
                            Cf[r6 * 128 + cH] = acc[m][n][i] + mub[half * 128 + cH];
                        }
                    }
                }
            }
            __syncthreads();
            #pragma unroll
            for (int ii = 0; ii < 8; ++ii) {
                int g   = ii * 256 + t;
                int r   = g >> 5;
                int cc  = g & 31;
                int row = rBase + r;
                if (row < N) {
                    *(float4*)(outF + (size_t)row * D + half * 128 + cc * 4) =
                        *(const float4*)(&Cf[r * 128 + cc * 4]);
                }
            }
            __syncthreads();
        }
    }
}

// ---------------------------------------------------------------------------

extern "C" void kernel_launch(void* const* d_in, const int* in_sizes, int n_in,
                              void* d_out, int out_size, void* d_ws, size_t ws_size,
                              hipStream_t stream)
{
    const float* emb  = (const float*)d_in[0];
    const int*   ei   = (const int*)  d_in[1];
    const int*   et   = (const int*)  d_in[2];
    const float* rel1 = (const float*)d_in[3];
    const float* Wi1  = (const float*)d_in[4];
    const float* Wo1  = (const float*)d_in[5];
    const float* Wl1  = (const float*)d_in[6];
    const float* b1   = (const float*)d_in[7];
    const float* rel2 = (const float*)d_in[8];
    const float* Wi2  = (const float*)d_in[9];
    const float* Wo2  = (const float*)d_in[10];
    const float* Wl2  = (const float*)d_in[11];
    const float* b2   = (const float*)d_in[12];
    const float* res  = (const float*)d_in[13];
    const float* muw  = (const float*)d_in[14];
    const float* mub  = (const float*)d_in[15];

    const int D = in_sizes[7];          // 256
    const int N = in_sizes[0] / D;      // 50000
    const int E = in_sizes[2];          // 320000
    const int R = in_sizes[3] / D;      // 400
    const int halfE = E / 2;
    const int* srcA = ei;
    const int* dstA = ei + E;
    const size_t DD = (size_t)D * D;

    char* ws = (char*)d_ws;
    size_t off = 0;
    auto alloc = [&](size_t bytes) -> char* {
        char* p = ws + off; off += (bytes + 255) & ~(size_t)255; return p;
    };
    const int nb1 = (N + 255) / 256;

    float*          norm   = (float*)          alloc((size_t)N * 4);
    int*            cnt    = (int*)            alloc((size_t)N * 4);
    int*            rowptr = (int*)            alloc((size_t)(N + 1) * 4);
    int*            cursor = (int*)            alloc((size_t)N * 4);
    int*            part   = (int*)            alloc((size_t)N * 4);
    int*            bsum   = (int*)            alloc(1024);
    unsigned*       erec   = (unsigned*)       alloc((size_t)E * 4);
    unsigned short* xb     = (unsigned short*) alloc((size_t)N * D * 2);
    unsigned short* h1b    = (unsigned short*) alloc((size_t)N * D * 2);
    unsigned char*  x8     = (unsigned char*)  alloc((size_t)N * D);
    unsigned char*  h18    = (unsigned char*)  alloc((size_t)N * D);
    unsigned char*  sIn8   = (unsigned char*)  alloc((size_t)N * D);
    unsigned char*  sOut8  = (unsigned char*)  alloc((size_t)N * D);
    unsigned short* r1b    = (unsigned short*) alloc((size_t)R * D * 2);
    unsigned short* r2b    = (unsigned short*) alloc((size_t)R * D * 2);
    unsigned char*  r18    = (unsigned char*)  alloc((size_t)R * D);
    unsigned char*  r28    = (unsigned char*)  alloc((size_t)R * D);
    unsigned short* fAll   = (unsigned short*) alloc(3 * DD * 2);   // Wl1, Wl2, mu
    unsigned char*  f8All  = (unsigned char*)  alloc(4 * DD);       // Wi1,Wo1,Wi2,Wo2
    if (off > ws_size) return;

    unsigned short* fWl1 = fAll;
    unsigned short* fWl2 = fAll + DD;
    unsigned short* fMu  = fAll + 2 * DD;
    unsigned char*  f8Wi1 = f8All;
    unsigned char*  f8Wo1 = f8All + DD;
    unsigned char*  f8Wi2 = f8All + 2 * DD;
    unsigned char*  f8Wo2 = f8All + 3 * DD;

    // --- CSR + norm ---
    hipMemsetAsync(cnt, 0, (size_t)N * 4, stream);
    k_hist   <<<(E + 255) / 256, 256, 0, stream>>>(dstA, cnt, E);
    k_norm   <<<nb1, 256, 0, stream>>>(cnt, norm, N);
    k_scan1  <<<nb1, 256, 0, stream>>>(cnt, part, bsum, N);
    k_scan2  <<<1,   256, 0, stream>>>(bsum, nb1);
    k_scan3  <<<nb1, 256, 0, stream>>>(part, bsum, rowptr, cursor, N, E);
    k_scatter<<<(E + 255) / 256, 256, 0, stream>>>(srcA, dstA, et, cursor, erec, E, halfE);

    // --- dtype prep ---
    long nd4 = (long)N * D / 4, rd4 = (long)R * D / 4;
    long tot4 = nd4 + 2 * rd4;
    k_cvtx3<<<(int)((tot4 + 255) / 256), 256, 0, stream>>>(
        emb, xb, x8, nd4, rel1, r1b, r18, rd4, rel2, r2b, r28, rd4);
    k_wfrag3<<<(int)(3 * DD / 256), 256, 0, stream>>>(Wl1, Wl2, muw, fAll);
    k_wfrag8<<<(int)(4 * DD / 1024), 256, 0, stream>>>(Wi1, Wo1, Wi2, Wo2, f8All);

    const int AB = (N + 3) / 4;
    const int NB = (N + 63) / 64;

    // --- layer 1 ---
    k_agg<<<AB, 256, 0, stream>>>(x8, r18, rowptr, erec, norm, sIn8, sOut8, N, D);
    k_gemm<false><<<NB, 256, 0, stream>>>(xb, sIn8, sOut8, fWl1, f8Wi1, f8Wo1, b1, res,
                                          nullptr, nullptr, nullptr, h1b, h18, N, D);

    // --- layer 2 + head ---
    k_agg<<<AB, 256, 0, stream>>>(h18, r28, rowptr, erec, norm, sIn8, sOut8, N, D);
    k_gemm<true><<<NB, 256, 0, stream>>>(h1b, sIn8, sOut8, fWl2, f8Wi2, f8Wo2, b2, res,
                                         fMu, mub, (float*)d_out, nullptr, nullptr, N, D);
}

// Round 15
// 204.772 us; speedup vs baseline: 1.2210x; 1.0068x over previous
//
#include <hip/hip_runtime.h>
#include <hip/hip_bf16.h>
#include <cstdint>
#include <cstddef>

// ---------------------------------------------------------------------------
// MGCN (2-layer relational GCN + linear head).
//
//   s_in[v]  = norm[v] * sum_{first-half edges,  dst=v} x[src]*rel[ty]
//   s_out[v] = norm[v] * sum_{second-half edges, dst=v} x[src]*rel[ty]
//   h        = x + res * tanh( x@W_loop + s_in@W_in + s_out@W_out + b )
//   out      = h2 @ mu_w + mu_b     (fused into layer-2 kernel)
//
// R14 + ALL-FP8 K-loop: A = [x8|sIn8|sOut8] (fp8), W_loop/W_in/W_out fp8
// fragment tables, uniform 12-step pipeline with 6-deep register A prefetch
// (5 loads in flight/wave) and 3 blocks/CU.  Residual path stays bf16.
// ---------------------------------------------------------------------------

typedef short bf16x8 __attribute__((ext_vector_type(8)));
typedef float f32x4  __attribute__((ext_vector_type(4)));
typedef float f32x2  __attribute__((ext_vector_type(2)));

__device__ __forceinline__ float b2f(unsigned short u) {
    union { unsigned u32; float f; } c; c.u32 = ((unsigned)u) << 16; return c.f;
}
__device__ __forceinline__ unsigned short f2b(float f) {
    union { float f; unsigned u; } c; c.f = f;
    unsigned r = c.u + 0x7FFFu + ((c.u >> 16) & 1u);   // RNE
    return (unsigned short)(r >> 16);
}
__device__ __forceinline__ float ftanh(float x) {
    float e = __expf(2.0f * x);
    return 1.0f - __fdividef(2.0f, e + 1.0f);
}

// f32 -> fp8 e4m3fn (OCP), RNE, saturating (software fallback).
__device__ __forceinline__ unsigned char f2e4m3(float f) {
    unsigned u = __float_as_uint(f);
    unsigned s = (u >> 24) & 0x80u;
    unsigned a = u & 0x7fffffffu;
    if (a >= 0x43e00000u) return (unsigned char)(s | 0x7eu);
    if (a < 0x3c800000u) {
        float m = __uint_as_float(a) * 512.0f;
        int q = (int)rintf(m);
        if (q == 8) return (unsigned char)(s | 0x08u);
        return (unsigned char)(s | (unsigned)q);
    }
    unsigned m = a & 0x7fffffu;
    unsigned e = a >> 23;
    unsigned r = m + 0x7ffffu + ((m >> 20) & 1u);
    if (r >= 0x800000u) { e += 1; r -= 0x800000u; }
    if (e > 127u + 8u) return (unsigned char)(s | 0x7eu);
    return (unsigned char)(s | ((e - 127u + 7u) << 3) | (r >> 20));
}

__device__ __forceinline__ unsigned pk8_4(float a, float b, float c, float d) {
#if __has_builtin(__builtin_amdgcn_cvt_pk_fp8_f32)
    int v = 0;
    v = __builtin_amdgcn_cvt_pk_fp8_f32(a, b, v, false);
    v = __builtin_amdgcn_cvt_pk_fp8_f32(c, d, v, true);
    return (unsigned)v;
#else
    return (unsigned)f2e4m3(a) | ((unsigned)f2e4m3(b) << 8)
         | ((unsigned)f2e4m3(c) << 16) | ((unsigned)f2e4m3(d) << 24);
#endif
}

__device__ __forceinline__ void dec4(unsigned u, float* f) {
#if __has_builtin(__builtin_amdgcn_cvt_pk_f32_fp8)
    f32x2 lo = __builtin_amdgcn_cvt_pk_f32_fp8((int)u, false);
    f32x2 hi = __builtin_amdgcn_cvt_pk_f32_fp8((int)u, true);
    f[0] = lo[0]; f[1] = lo[1]; f[2] = hi[0]; f[3] = hi[1];
#else
    #pragma unroll
    for (int i = 0; i < 4; ++i) {
        unsigned b = (u >> (8 * i)) & 0xffu;
        unsigned em = b & 0x7fu;
        float mag;
        if (em >= 8u) mag = __uint_as_float((((em >> 3) + 120u) << 23) | ((em & 7u) << 20));
        else          mag = (float)em * 0.001953125f;
        f[i] = (b & 0x80u) ? -mag : mag;
    }
#endif
}

// ---- CSR construction ------------------------------------------------------

__global__ void k_hist(const int* __restrict__ dst, int* __restrict__ cnt, int E) {
    int i = blockIdx.x * blockDim.x + threadIdx.x;
    if (i < E) atomicAdd(&cnt[dst[i]], 1);
}

__global__ void k_norm(const int* __restrict__ cnt, float* __restrict__ norm, int N) {
    int i = blockIdx.x * blockDim.x + threadIdx.x;
    if (i < N) norm[i] = 1.0f / fmaxf((float)cnt[i], 1.0f);
}

__global__ void k_scan1(const int* __restrict__ cnt, int* __restrict__ part,
                        int* __restrict__ bsum, int N) {
    __shared__ int s[256];
    int i = blockIdx.x * 256 + threadIdx.x;
    int v = (i < N) ? cnt[i] : 0;
    s[threadIdx.x] = v; __syncthreads();
    #pragma unroll
    for (int o = 1; o < 256; o <<= 1) {
        int t = (threadIdx.x >= o) ? s[threadIdx.x - o] : 0;
        __syncthreads();
        s[threadIdx.x] += t;
        __syncthreads();
    }
    if (i < N) part[i] = s[threadIdx.x] - v;
    if (threadIdx.x == 255) bsum[blockIdx.x] = s[255];
}

__global__ void k_scan2(int* __restrict__ bsum, int nb) {
    __shared__ int s[256];
    int v = (threadIdx.x < nb) ? bsum[threadIdx.x] : 0;
    s[threadIdx.x] = v; __syncthreads();
    #pragma unroll
    for (int o = 1; o < 256; o <<= 1) {
        int t = (threadIdx.x >= o) ? s[threadIdx.x - o] : 0;
        __syncthreads();
        s[threadIdx.x] += t;
        __syncthreads();
    }
    if (threadIdx.x < nb) bsum[threadIdx.x] = s[threadIdx.x] - v;
}

__global__ void k_scan3(const int* __restrict__ part, const int* __restrict__ bsum,
                        int* __restrict__ rowptr, int* __restrict__ cursor, int N, int E) {
    int i = blockIdx.x * 256 + threadIdx.x;
    if (i < N) {
        int r = part[i] + bsum[blockIdx.x];
        rowptr[i] = r; cursor[i] = r;
    }
    if (i == 0) rowptr[N] = E;
}

__global__ void k_scatter(const int* __restrict__ src, const int* __restrict__ dst,
                          const int* __restrict__ et, int* __restrict__ cursor,
                          unsigned* __restrict__ erec, int E, int halfE) {
    int e = blockIdx.x * blockDim.x + threadIdx.x;
    if (e < E) {
        int d = dst[e];
        int pos = atomicAdd(&cursor[d], 1);
        unsigned rec = (unsigned)src[e] | ((unsigned)et[e] << 16)
                     | ((e >= halfE) ? 0x80000000u : 0u);
        erec[pos] = rec;
    }
}

// ---- dtype prep ------------------------------------------------------------

__global__ void k_cvtx3(const float* __restrict__ s0, unsigned short* __restrict__ d0,
                        unsigned char* __restrict__ e0, long n0,
                        const float* __restrict__ s1, unsigned short* __restrict__ d1,
                        unsigned char* __restrict__ e1, long n1,
                        const float* __restrict__ s2, unsigned short* __restrict__ d2,
                        unsigned char* __restrict__ e2, long n2) {
    long i = (long)blockIdx.x * blockDim.x + threadIdx.x;
    const float* s; unsigned short* d; unsigned char* e; long j = i;
    if (j < n0) { s = s0; d = d0; e = e0; }
    else {
        j -= n0;
        if (j < n1) { s = s1; d = d1; e = e1; }
        else { j -= n1; if (j >= n2) return; s = s2; d = d2; e = e2; }
    }
    float4 v = ((const float4*)s)[j];
    ushort4 o;
    o.x = f2b(v.x); o.y = f2b(v.y); o.z = f2b(v.z); o.w = f2b(v.w);
    ((ushort4*)d)[j] = o;
    ((unsigned*)e)[j] = pk8_4(v.x, v.y, v.z, v.w);
}

// bf16 fragment table: mu_w only
__global__ void k_wfrag1(const float* __restrict__ W, unsigned short* __restrict__ out) {
    int o = blockIdx.x * 256 + threadIdx.x;      // grid = 65536/256
    int j  = o & 7;
    int l  = (o >> 3) & 63;
    int nn = (o >> 9) & 15;
    int kg = o >> 13;
    int k = kg * 32 + (l >> 4) * 8 + j;
    int n = nn * 16 + (l & 15);
    out[o] = f2b(W[k * 256 + n]);
}

// fp8 fragment tables: Wl1, Wi1, Wo1, Wl2, Wi2, Wo2 (8-byte frags)
__global__ void k_wfrag8(const float* __restrict__ w0, const float* __restrict__ w1,
                         const float* __restrict__ w2, const float* __restrict__ w3,
                         const float* __restrict__ w4, const float* __restrict__ w5,
                         unsigned char* __restrict__ out) {
    int o = (blockIdx.x * 256 + threadIdx.x) * 4;    // grid = 6*65536/1024
    int mi = o >> 16;
    int r  = o & 65535;
    const float* W = (mi == 0) ? w0 : (mi == 1) ? w1 : (mi == 2) ? w2 :
                     (mi == 3) ? w3 : (mi == 4) ? w4 : w5;
    int j0 = r & 7;
    int l  = (r >> 3) & 63;
    int nn = (r >> 9) & 15;
    int kg = r >> 13;
    int n  = nn * 16 + (l & 15);
    int kb = kg * 32 + (l >> 4) * 8 + j0;
    *(unsigned*)(out + o) = pk8_4(W[(kb + 0) * 256 + n], W[(kb + 1) * 256 + n],
                                  W[(kb + 2) * 256 + n], W[(kb + 3) * 256 + n]);
}

// ---- CSR gather aggregation: fp8 in/out, 4-edge pipeline (R14, verified) ---

__global__ __launch_bounds__(256)
void k_agg(const unsigned char* __restrict__ x8, const unsigned char* __restrict__ rel8,
           const int* __restrict__ rowptr, const unsigned* __restrict__ erec,
           const float* __restrict__ norm,
           unsigned char* __restrict__ sIn8, unsigned char* __restrict__ sOut8,
           int N, int D)
{
    const int w = threadIdx.x >> 6, l = threadIdx.x & 63;
    const int v = blockIdx.x * 4 + w;
    if (v >= N) return;
    const int rs = rowptr[v], re = rowptr[v + 1];
    const float nm = norm[v];

    float ai0 = 0, ai1 = 0, ai2 = 0, ai3 = 0;
    float ao0 = 0, ao1 = 0, ao2 = 0, ao3 = 0;

    unsigned c0 = (rs     < re) ? erec[rs]     : 0u;
    unsigned c1 = (rs + 1 < re) ? erec[rs + 1] : 0u;
    unsigned c2 = (rs + 2 < re) ? erec[rs + 2] : 0u;
    unsigned c3 = (rs + 3 < re) ? erec[rs + 3] : 0u;
    int i = rs;
    while (i + 4 <= re) {
        unsigned m0 = (i + 4 < re) ? erec[i + 4] : 0u;
        unsigned m1 = (i + 5 < re) ? erec[i + 5] : 0u;
        unsigned m2 = (i + 6 < re) ? erec[i + 6] : 0u;
        unsigned m3 = (i + 7 < re) ? erec[i + 7] : 0u;
        unsigned xu0 = *(const unsigned*)(x8   + (size_t)(c0 & 0xffff) * 256 + l * 4);
        unsigned ru0 = *(const unsigned*)(rel8 + (size_t)((c0 >> 16) & 0x7fff) * 256 + l * 4);
        unsigned xu1 = *(const unsigned*)(x8   + (size_t)(c1 & 0xffff) * 256 + l * 4);
        unsigned ru1 = *(const unsigned*)(rel8 + (size_t)((c1 >> 16) & 0x7fff) * 256 + l * 4);
        unsigned xu2 = *(const unsigned*)(x8   + (size_t)(c2 & 0xffff) * 256 + l * 4);
        unsigned ru2 = *(const unsigned*)(rel8 + (size_t)((c2 >> 16) & 0x7fff) * 256 + l * 4);
        unsigned xu3 = *(const unsigned*)(x8   + (size_t)(c3 & 0xffff) * 256 + l * 4);
        unsigned ru3 = *(const unsigned*)(rel8 + (size_t)((c3 >> 16) & 0x7fff) * 256 + l * 4);
        float xf[4], rf[4];
        dec4(xu0, xf); dec4(ru0, rf);
        if (c0 >> 31) { ao0 += xf[0]*rf[0]; ao1 += xf[1]*rf[1]; ao2 += xf[2]*rf[2]; ao3 += xf[3]*rf[3]; }
        else          { ai0 += xf[0]*rf[0]; ai1 += xf[1]*rf[1]; ai2 += xf[2]*rf[2]; ai3 += xf[3]*rf[3]; }
        dec4(xu1, xf); dec4(ru1, rf);
        if (c1 >> 31) { ao0 += xf[0]*rf[0]; ao1 += xf[1]*rf[1]; ao2 += xf[2]*rf[2]; ao3 += xf[3]*rf[3]; }
        else          { ai0 += xf[0]*rf[0]; ai1 += xf[1]*rf[1]; ai2 += xf[2]*rf[2]; ai3 += xf[3]*rf[3]; }
        dec4(xu2, xf); dec4(ru2, rf);
        if (c2 >> 31) { ao0 += xf[0]*rf[0]; ao1 += xf[1]*rf[1]; ao2 += xf[2]*rf[2]; ao3 += xf[3]*rf[3]; }
        else          { ai0 += xf[0]*rf[0]; ai1 += xf[1]*rf[1]; ai2 += xf[2]*rf[2]; ai3 += xf[3]*rf[3]; }
        dec4(xu3, xf); dec4(ru3, rf);
        if (c3 >> 31) { ao0 += xf[0]*rf[0]; ao1 += xf[1]*rf[1]; ao2 += xf[2]*rf[2]; ao3 += xf[3]*rf[3]; }
        else          { ai0 += xf[0]*rf[0]; ai1 += xf[1]*rf[1]; ai2 += xf[2]*rf[2]; ai3 += xf[3]*rf[3]; }
        c0 = m0; c1 = m1; c2 = m2; c3 = m3; i += 4;
    }
    #pragma unroll
    for (int j = 0; j < 3; ++j) {
        if (i + j < re) {
            unsigned cur = (j == 0) ? c0 : (j == 1) ? c1 : c2;
            unsigned xu = *(const unsigned*)(x8   + (size_t)(cur & 0xffff) * 256 + l * 4);
            unsigned ru = *(const unsigned*)(rel8 + (size_t)((cur >> 16) & 0x7fff) * 256 + l * 4);
            float xf[4], rf[4];
            dec4(xu, xf); dec4(ru, rf);
            if (cur >> 31) { ao0 += xf[0]*rf[0]; ao1 += xf[1]*rf[1]; ao2 += xf[2]*rf[2]; ao3 += xf[3]*rf[3]; }
            else           { ai0 += xf[0]*rf[0]; ai1 += xf[1]*rf[1]; ai2 += xf[2]*rf[2]; ai3 += xf[3]*rf[3]; }
        }
    }

    *(unsigned*)(sIn8  + (size_t)v * 256 + l * 4) = pk8_4(ai0 * nm, ai1 * nm, ai2 * nm, ai3 * nm);
    *(unsigned*)(sOut8 + (size_t)v * 256 + l * 4) = pk8_4(ao0 * nm, ao1 * nm, ao2 * nm, ao3 * nm);
}

// ---- all-fp8 GEMM: uniform 12-step pipeline, 6-deep A prefetch -------------

#define FB  do { asm volatile("s_waitcnt lgkmcnt(0)" ::: "memory");             \
                 __builtin_amdgcn_sched_barrier(0);                             \
                 __builtin_amdgcn_s_barrier();                                  \
                 __builtin_amdgcn_sched_barrier(0); } while (0)

#define WR8(AtN, R0)     do { *(uint4*)((AtN) + wf8b) = R0; } while (0)
#define LD8(R0, SRC, CB) do { R0 = *(const uint4*)((SRC) + gf8 + (CB)*64); } while (0)

#define PB8(Bn, TBL, CB)                                                        \
  do { _Pragma("unroll")                                                        \
       for (int kk_ = 0; kk_ < 2; ++kk_) {                                      \
         _Pragma("unroll")                                                      \
         for (int n_ = 0; n_ < 4; ++n_)                                         \
           Bn[kk_*4+n_] = *(const long long*)((TBL) +                           \
               ((((CB)*2+kk_)*16 + (w*4+n_))*64 + l)*8);                        \
       } } while (0)

#define MM8(AtC, Bc)                                                            \
  do { const char* A8_ = (const char*)(AtC);                                    \
       _Pragma("unroll")                                                        \
       for (int kk_ = 0; kk_ < 2; ++kk_) {                                      \
         long long a_[4];                                                       \
         _Pragma("unroll")                                                      \
         for (int m_ = 0; m_ < 4; ++m_) {                                       \
           int rm_ = 16*m_ + lr; int ch_ = (kk_*4+lq) ^ (rm_ & 6);              \
           a_[m_] = *(const long long*)(A8_ + rm_*64 + ch_*8);                  \
         }                                                                      \
         _Pragma("unroll")                                                      \
         for (int m_ = 0; m_ < 4; ++m_) {                                       \
           _Pragma("unroll")                                                    \
           for (int n_ = 0; n_ < 4; ++n_)                                       \
             acc[m_][n_] = __builtin_amdgcn_mfma_f32_16x16x32_fp8_fp8(          \
                 a_[m_], Bc[kk_*4+n_], acc[m_][n_], 0, 0, 0);                   \
         } } } while (0)

template <bool HEAD>
__global__ __launch_bounds__(256, 3)
void k_gemm(const unsigned char*  __restrict__ a8,     // [N,256] fp8 x / h1 (A op)
            const unsigned short* __restrict__ ares,   // [N,256] bf16 residual
            const unsigned char*  __restrict__ s8i,    // [N,256] fp8 sIn
            const unsigned char*  __restrict__ s8o,    // [N,256] fp8 sOut
            const unsigned char*  __restrict__ W8L,    // fp8 frag (W_loop)
            const unsigned char*  __restrict__ W8I,    // fp8 frag (W_in)
            const unsigned char*  __restrict__ W8O,    // fp8 frag (W_out)
            const float* __restrict__ bias,
            const float* __restrict__ resPtr,
            const unsigned short* __restrict__ WfMu,   // bf16 frag (HEAD)
            const float* __restrict__ mub,             // (HEAD)
            float* __restrict__ outF,                  // (HEAD)
            unsigned short* __restrict__ outB,         // (!HEAD)
            unsigned char* __restrict__ outB8,         // (!HEAD) fp8 h copy
            int N, int D)
{
    __shared__ unsigned char ldsb[HEAD ? 32768 : 16384];
    unsigned char* At0 = ldsb;
    unsigned char* At1 = ldsb + 4096;

    const int t = threadIdx.x;
    const int rBase = blockIdx.x * 64;

    const int w  = t >> 6;
    const int l  = t & 63;
    const int lr = l & 15;
    const int lq = l >> 4;

    // fp8 staging geometry (one 16B chunk / thread = 16 cols of a row)
    const int rf  = t >> 2;
    const int qf  = t & 3;
    const int wf8b = rf * 64 + (((2 * qf) ^ (rf & 6)) * 8);
    const size_t gf8 = (size_t)min(rBase + rf, N - 1) * 256 + qf * 16;

    f32x4 acc[4][4] = {};
    uint4 Ra, Rb, Rc, Rd, Re, Rf;
    long long B8a[8], B8b[8];

    // prologue: tiles 0..5 in flight; tile0 -> At0; B(step0)
    LD8(Ra, a8, 0); LD8(Rb, a8, 1); LD8(Rc, a8, 2); LD8(Rd, a8, 3);
    LD8(Re, s8i, 0); LD8(Rf, s8i, 1);
    PB8(B8a, W8L, 0);
    WR8(At0, Ra);
    FB;

    /*s0 */ WR8(At1, Rb); PB8(B8b, W8L, 1); MM8(At0, B8a); LD8(Ra, s8i, 2); FB;
    /*s1 */ WR8(At0, Rc); PB8(B8a, W8L, 2); MM8(At1, B8b); LD8(Rb, s8i, 3); FB;
    /*s2 */ WR8(At1, Rd); PB8(B8b, W8L, 3); MM8(At0, B8a); LD8(Rc, s8o, 0); FB;
    /*s3 */ WR8(At0, Re); PB8(B8a, W8I, 0); MM8(At1, B8b); LD8(Rd, s8o, 1); FB;
    /*s4 */ WR8(At1, Rf); PB8(B8b, W8I, 1); MM8(At0, B8a); LD8(Re, s8o, 2); FB;
    /*s5 */ WR8(At0, Ra); PB8(B8a, W8I, 2); MM8(At1, B8b); LD8(Rf, s8o, 3); FB;
    /*s6 */ WR8(At1, Rb); PB8(B8b, W8I, 3); MM8(At0, B8a); FB;
    /*s7 */ WR8(At0, Rc); PB8(B8a, W8O, 0); MM8(At1, B8b); FB;
    /*s8 */ WR8(At1, Rd); PB8(B8b, W8O, 1); MM8(At0, B8a); FB;
    /*s9 */ WR8(At0, Re); PB8(B8a, W8O, 2); MM8(At1, B8b); FB;
    /*s10*/ WR8(At1, Rf); PB8(B8b, W8O, 3); MM8(At0, B8a); FB;
    /*s11*/                                 MM8(At1, B8b); FB;

    const int rb4 = lq * 4;
    const float resv = resPtr[0];

    if (!HEAD) {
        // ---- coalesced epilogue: stage res*tanh(acc+bias) in LDS halves ----
        unsigned short* C = (unsigned short*)ldsb;   // 64 x 128 bf16 per half
        #pragma unroll
        for (int half = 0; half < 2; ++half) {
            if ((w >> 1) == half) {
                #pragma unroll
                for (int m = 0; m < 4; ++m) {
                    #pragma unroll
                    for (int i = 0; i < 4; ++i) {
                        int r6 = 16 * m + rb4 + i;
                        #pragma unroll
                        for (int n = 0; n < 4; ++n) {
                            int cH = (w & 1) * 64 + lr + 16 * n;
                            float v = acc[m][n][i] + bias[half * 128 + cH];
                            C[r6 * 128 + cH] = f2b(resv * ftanh(v));
                        }
                    }
                }
            }
            __syncthreads();
            #pragma unroll
            for (int ii = 0; ii < 4; ++ii) {
                int g   = ii * 256 + t;
                int r   = g >> 4;
                int cc  = g & 15;
                int row = rBase + r;
                if (row < N) {
                    bf16x8 sv = *(const bf16x8*)(&C[r * 128 + cc * 8]);
                    const unsigned short* ar = ares + (size_t)row * D + half * 128 + cc * 8;
                    uint4 av = *(const uint4*)ar;
                    unsigned aw[4] = { av.x, av.y, av.z, av.w };
                    unsigned ow[4];
                    float hv[8];
                    #pragma unroll
                    for (int p = 0; p < 4; ++p) {
                        float h0 = b2f((unsigned short)(aw[p] & 0xffff)) + b2f((unsigned short)sv[2 * p]);
                        float h1 = b2f((unsigned short)(aw[p] >> 16))    + b2f((unsigned short)sv[2 * p + 1]);
                        hv[2 * p] = h0; hv[2 * p + 1] = h1;
                        ow[p] = (unsigned)f2b(h0) | ((unsigned)f2b(h1) << 16);
                    }
                    *(uint4*)(outB + (size_t)row * D + half * 128 + cc * 8) =
                        make_uint4(ow[0], ow[1], ow[2], ow[3]);
                    uint2 q;
                    q.x = pk8_4(hv[0], hv[1], hv[2], hv[3]);
                    q.y = pk8_4(hv[4], hv[5], hv[6], hv[7]);
                    *(uint2*)(outB8 + (size_t)row * 256 + half * 128 + cc * 8) = q;
                }
            }
            __syncthreads();
        }
    } else {
        // ---- HEAD: h2 -> swizzled LDS bf16 tile, then out = h2 @ WfMu + mub ----
        unsigned short* lds = (unsigned short*)ldsb;   // 64 x 256 bf16
        #pragma unroll
        for (int m = 0; m < 4; ++m) {
            #pragma unroll
            for (int i = 0; i < 4; ++i) {
                int row = rBase + 16 * m + rb4 + i;
                if (row < N) {
                    size_t base = (size_t)row * D + w * 64 + lr;
                    int r6 = 16 * m + rb4 + i;
                    #pragma unroll
                    for (int n = 0; n < 4; ++n) {
                        int   c = w * 64 + lr + 16 * n;
                        float v = acc[m][n][i] + bias[c];
                        float h = b2f(ares[base + 16 * n]) + resv * ftanh(v);
                        lds[r6 * 256 + (c ^ ((r6 & 7) << 3))] = f2b(h);
                    }
                }
            }
        }
        __syncthreads();
        #pragma unroll
        for (int m = 0; m < 4; ++m) {
            #pragma unroll
            for (int n = 0; n < 4; ++n)
                acc[m][n] = (f32x4){0.f, 0.f, 0.f, 0.f};
        }

        #pragma unroll
        for (int s2 = 0; s2 < 4; ++s2) {
            #pragma unroll
            for (int kk = 0; kk < 2; ++kk) {
                const int kg = s2 * 2 + kk;
                bf16x8 a_[4], b_[4];
                #pragma unroll
                for (int m = 0; m < 4; ++m) {
                    int rm = 16 * m + lr;
                    int ch = (s2 * 8 + kk * 4 + lq) ^ (rm & 7);
                    a_[m] = *(const bf16x8*)(&lds[rm * 256 + ch * 8]);
                }
                #pragma unroll
                for (int n = 0; n < 4; ++n)
                    b_[n] = *(const bf16x8*)(WfMu + (((kg * 16 + (w * 4 + n)) * 64 + l) * 8));
                #pragma unroll
                for (int m = 0; m < 4; ++m) {
                    #pragma unroll
                    for (int n = 0; n < 4; ++n)
                        acc[m][n] = __builtin_amdgcn_mfma_f32_16x16x32_bf16(a_[m], b_[n], acc[m][n], 0, 0, 0);
                }
            }
        }

        __syncthreads();
        float* Cf = (float*)ldsb;                     // 64 x 128 f32 per half
        #pragma unroll
        for (int half = 0; half < 2; ++half) {
            if ((w >> 1) == half) {
                #pragma unroll
                for (int m = 0; m < 4; ++m) {
                    #pragma unroll
                    for (int i = 0; i < 4; ++i) {
                        int r6 = 16 * m + rb4 + i;
                        #pragma unroll
                        for (int n = 0; n < 4; ++n) {
                            int cH = (w & 1) * 64 + lr + 16 * n;
                            Cf[r6 * 128 + cH] = acc[m][n][i] + mub[half * 128 + cH];
                        }
                    }
                }
            }
            __syncthreads();
            #pragma unroll
            for (int ii = 0; ii < 8; ++ii) {
                int g   = ii * 256 + t;
                int r   = g >> 5;
                int cc  = g & 31;
                int row = rBase + r;
                if (row < N) {
                    *(float4*)(outF + (size_t)row * D + half * 128 + cc * 4) =
                        *(const float4*)(&Cf[r * 128 + cc * 4]);
                }
            }
            __syncthreads();
        }
    }
}

// ---------------------------------------------------------------------------

extern "C" void kernel_launch(void* const* d_in, const int* in_sizes, int n_in,
                              void* d_out, int out_size, void* d_ws, size_t ws_size,
                              hipStream_t stream)
{
    const float* emb  = (const float*)d_in[0];
    const int*   ei   = (const int*)  d_in[1];
    const int*   et   = (const int*)  d_in[2];
    const float* rel1 = (const float*)d_in[3];
    const float* Wi1  = (const float*)d_in[4];
    const float* Wo1  = (const float*)d_in[5];
    const float* Wl1  = (const float*)d_in[6];
    const float* b1   = (const float*)d_in[7];
    const float* rel2 = (const float*)d_in[8];
    const float* Wi2  = (const float*)d_in[9];
    const float* Wo2  = (const float*)d_in[10];
    const float* Wl2  = (const float*)d_in[11];
    const float* b2   = (const float*)d_in[12];
    const float* res  = (const float*)d_in[13];
    const float* muw  = (const float*)d_in[14];
    const float* mub  = (const float*)d_in[15];

    const int D = in_sizes[7];          // 256
    const int N = in_sizes[0] / D;      // 50000
    const int E = in_sizes[2];          // 320000
    const int R = in_sizes[3] / D;      // 400
    const int halfE = E / 2;
    const int* srcA = ei;
    const int* dstA = ei + E;
    const size_t DD = (size_t)D * D;

    char* ws = (char*)d_ws;
    size_t off = 0;
    auto alloc = [&](size_t bytes) -> char* {
        char* p = ws + off; off += (bytes + 255) & ~(size_t)255; return p;
    };
    const int nb1 = (N + 255) / 256;

    float*          norm   = (float*)          alloc((size_t)N * 4);
    int*            cnt    = (int*)            alloc((size_t)N * 4);
    int*            rowptr = (int*)            alloc((size_t)(N + 1) * 4);
    int*            cursor = (int*)            alloc((size_t)N * 4);
    int*            part   = (int*)            alloc((size_t)N * 4);
    int*            bsum   = (int*)            alloc(1024);
    unsigned*       erec   = (unsigned*)       alloc((size_t)E * 4);
    unsigned short* xb     = (unsigned short*) alloc((size_t)N * D * 2);
    unsigned short* h1b    = (unsigned short*) alloc((size_t)N * D * 2);
    unsigned char*  x8     = (unsigned char*)  alloc((size_t)N * D);
    unsigned char*  h18    = (unsigned char*)  alloc((size_t)N * D);
    unsigned char*  sIn8   = (unsigned char*)  alloc((size_t)N * D);
    unsigned char*  sOut8  = (unsigned char*)  alloc((size_t)N * D);
    unsigned short* r1b    = (unsigned short*) alloc((size_t)R * D * 2);
    unsigned short* r2b    = (unsigned short*) alloc((size_t)R * D * 2);
    unsigned char*  r18    = (unsigned char*)  alloc((size_t)R * D);
    unsigned char*  r28    = (unsigned char*)  alloc((size_t)R * D);
    unsigned short* fMu    = (unsigned short*) alloc(DD * 2);
    unsigned char*  f8All  = (unsigned char*)  alloc(6 * DD);
    if (off > ws_size) return;

    unsigned char* f8Wl1 = f8All;
    unsigned char* f8Wi1 = f8All + DD;
    unsigned char* f8Wo1 = f8All + 2 * DD;
    unsigned char* f8Wl2 = f8All + 3 * DD;
    unsigned char* f8Wi2 = f8All + 4 * DD;
    unsigned char* f8Wo2 = f8All + 5 * DD;

    // --- CSR + norm ---
    hipMemsetAsync(cnt, 0, (size_t)N * 4, stream);
    k_hist   <<<(E + 255) / 256, 256, 0, stream>>>(dstA, cnt, E);
    k_norm   <<<nb1, 256, 0, stream>>>(cnt, norm, N);
    k_scan1  <<<nb1, 256, 0, stream>>>(cnt, part, bsum, N);
    k_scan2  <<<1,   256, 0, stream>>>(bsum, nb1);
    k_scan3  <<<nb1, 256, 0, stream>>>(part, bsum, rowptr, cursor, N, E);
    k_scatter<<<(E + 255) / 256, 256, 0, stream>>>(srcA, dstA, et, cursor, erec, E, halfE);

    // --- dtype prep ---
    long nd4 = (long)N * D / 4, rd4 = (long)R * D / 4;
    long tot4 = nd4 + 2 * rd4;
    k_cvtx3<<<(int)((tot4 + 255) / 256), 256, 0, stream>>>(
        emb, xb, x8, nd4, rel1, r1b, r18, rd4, rel2, r2b, r28, rd4);
    k_wfrag1<<<(int)(DD / 256), 256, 0, stream>>>(muw, fMu);
    k_wfrag8<<<(int)(6 * DD / 1024), 256, 0, stream>>>(Wl1, Wi1, Wo1, Wl2, Wi2, Wo2, f8All);

    const int AB = (N + 3) / 4;
    const int NB = (N + 63) / 64;

    // --- layer 1 ---
    k_agg<<<AB, 256, 0, stream>>>(x8, r18, rowptr, erec, norm, sIn8, sOut8, N, D);
    k_gemm<false><<<NB, 256, 0, stream>>>(x8, xb, sIn8, sOut8, f8Wl1, f8Wi1, f8Wo1, b1, res,
                                          nullptr, nullptr, nullptr, h1b, h18, N, D);

    // --- layer 2 + head ---
    k_agg<<<AB, 256, 0, stream>>>(h18, r28, rowptr, erec, norm, sIn8, sOut8, N, D);
    k_gemm<true><<<NB, 256, 0, stream>>>(h18, h1b, sIn8, sOut8, f8Wl2, f8Wi2, f8Wo2, b2, res,
                                         fMu, mub, (float*)d_out, nullptr, nullptr, N, D);
}